// Round 5
// baseline (998.854 us; speedup 1.0000x reference)
//
#include <hip/hip_runtime.h>

typedef unsigned short u16;
typedef unsigned int u32;
using short8  = __attribute__((ext_vector_type(8))) short;
using floatx4 = __attribute__((ext_vector_type(4))) float;

#define NB 32
#define SEQ 1024
#define EMB 512
#define NH 8
#define HD 64
#define NLAYER 2
#define M_ROWS (NB * SEQ)   // 32768

__device__ __forceinline__ float bf2f(u16 u) {
  union { u32 i; float f; } v; v.i = ((u32)u) << 16; return v.f;
}
__device__ __forceinline__ u16 f2bf(float f) {
  union { float f; u32 i; } v; v.f = f;
  u32 r = v.i + 0x7fffu + ((v.i >> 16) & 1u);
  return (u16)(r >> 16);
}

// async global->LDS, 16B per lane. LDS dest = wave-uniform base + lane*16.
typedef __attribute__((address_space(3))) unsigned int lds_u32_t;
typedef __attribute__((address_space(1))) const unsigned int gbl_u32_t;
__device__ __forceinline__ void gload16(void* lds, const void* g) {
  gbl_u32_t* gp = (gbl_u32_t*)(unsigned long long)g;
  lds_u32_t* lp = (lds_u32_t*)(unsigned int)(unsigned long long)lds;
  __builtin_amdgcn_global_load_lds(gp, lp, 16, 0, 0);
}

// ---------------- weight pre-transpose + fp32->bf16: W[K,N] -> Bt[N,K] ------
__global__ void prep_weights(const float* __restrict__ Wq, const float* __restrict__ Wk,
                             const float* __restrict__ Wv, const float* __restrict__ Wo,
                             u16* __restrict__ WtQKV, u16* __restrict__ WtO) {
  int idx = blockIdx.x * 256 + threadIdx.x;
  const int QKV_TOT = NLAYER * 3 * EMB * EMB;
  if (idx < QKV_TOT) {
    int l = idx / (3 * EMB * EMB);
    int rem = idx % (3 * EMB * EMB);
    int n = rem / EMB, kk = rem % EMB;
    int w = n >> 9, e = n & 511;
    const float* src = (w == 0) ? Wq : (w == 1) ? Wk : Wv;
    WtQKV[idx] = f2bf(src[((size_t)l * EMB + kk) * EMB + e]);
  } else {
    int j = idx - QKV_TOT;
    int l = j / (EMB * EMB);
    int rem = j % (EMB * EMB);
    int n = rem / EMB, kk = rem % EMB;
    WtO[j] = f2bf(Wo[((size_t)l * EMB + kk) * EMB + n]);
  }
}

// ---------------- embedding + positional encoding (fp32 in, bf16 out) -------
__global__ void embed_pe(const int* __restrict__ inp, const float* __restrict__ table,
                         u16* __restrict__ x) {
  int row = blockIdx.x;
  int tok = inp[row];
  int s = row & (SEQ - 1);
  const float negln = -9.210340371976184f / (float)EMB;
  for (int e = threadIdx.x; e < EMB; e += blockDim.x) {
    float val = table[(size_t)tok * EMB + e];
    int i = e >> 1;
    float dt = expf((float)(2 * i) * negln);
    float ang = (float)s * dt;
    float pe = (e & 1) ? cosf(ang) : sinf(ang);
    x[(size_t)row * EMB + e] = f2bf(val + pe);
  }
}

// ---------------- GEMM: C[M,N] = A[M,K] @ Bt[N,K]^T + bias ------------------
// mode 0: N=1536. Q,K sections -> [B,H,S,D] (col-contiguous stores).
//         V section (bn0>=1024): OPERAND-SWAPPED MFMA -> C transposed in regs
//         -> [B,H,D,S] stores are sid-contiguous. (X·Wv^T)^T = Wv·X^T.
// mode 1: N=512,  x = x + relu(C + bias)   (in place, out0 == resid)
#define BK 32

__global__ __launch_bounds__(256) void gemm_bt(
    const u16* __restrict__ A, const u16* __restrict__ Bt, int K, int mode,
    const float* bias0, const float* bias1, const float* bias2,
    u16* out0, u16* out1, u16* out2, const u16* resid, int Nstride) {
  __shared__ u16 sA[128][BK];
  __shared__ u16 sB[128][BK];
  int tid = threadIdx.x;
  int wave = tid >> 6, lane = tid & 63;
  int quad = lane >> 4, l16 = lane & 15;
  int wm = wave >> 1, wn = wave & 1;
  int bn0 = blockIdx.x * 128, bm0 = blockIdx.y * 128;
  bool vswap = (mode == 0) && (bn0 >= 1024);

  floatx4 acc[4][4];
#pragma unroll
  for (int i = 0; i < 4; ++i)
#pragma unroll
    for (int j = 0; j < 4; ++j) acc[i][j] = (floatx4){0.f, 0.f, 0.f, 0.f};

  int rb = wave * 32;                 // this wave stages rows rb..rb+31
  int lrow = lane >> 2;               // 0..15
  int scg = lane & 3;                 // LDS column-group slot

  for (int k0 = 0; k0 < K; k0 += BK) {
#pragma unroll
    for (int c = 0; c < 2; ++c) {
      int srow = c * 16 + lrow;
      int gcg = (scg ^ (srow & 3)) * 8;
      gload16(&sA[rb + c * 16][0], &A[(size_t)(bm0 + rb + srow) * K + k0 + gcg]);
      gload16(&sB[rb + c * 16][0], &Bt[(size_t)(bn0 + rb + srow) * K + k0 + gcg]);
    }
    __syncthreads();
    short8 af[4], bfr[4];
    int rcg = (quad ^ (l16 & 3)) * 8;
#pragma unroll
    for (int mi = 0; mi < 4; ++mi)
      af[mi] = *(const short8*)&sA[wm * 64 + mi * 16 + l16][rcg];
#pragma unroll
    for (int ni = 0; ni < 4; ++ni)
      bfr[ni] = *(const short8*)&sB[wn * 64 + ni * 16 + l16][rcg];
    if (!vswap) {
#pragma unroll
      for (int mi = 0; mi < 4; ++mi)
#pragma unroll
        for (int ni = 0; ni < 4; ++ni)
          acc[mi][ni] = __builtin_amdgcn_mfma_f32_16x16x32_bf16(af[mi], bfr[ni], acc[mi][ni], 0, 0, 0);
    } else {
#pragma unroll
      for (int mi = 0; mi < 4; ++mi)
#pragma unroll
        for (int ni = 0; ni < 4; ++ni)
          acc[mi][ni] = __builtin_amdgcn_mfma_f32_16x16x32_bf16(bfr[ni], af[mi], acc[mi][ni], 0, 0, 0);
    }
    __syncthreads();
  }

#pragma unroll
  for (int mi = 0; mi < 4; ++mi) {
#pragma unroll
    for (int ni = 0; ni < 4; ++ni) {
#pragma unroll
      for (int r = 0; r < 4; ++r) {
        float v = acc[mi][ni][r];
        if (vswap) {
          // D rows = weight rows (d), D cols = x rows (sid)
          int n = bn0 + wn * 64 + ni * 16 + quad * 4 + r;
          int m = bm0 + wm * 64 + mi * 16 + l16;
          int e = n & 511, h = (n >> 6) & 7, d = n & 63;
          int b = m >> 10, sid = m & 1023;
          v += bias2[e];
          out2[((size_t)(b * NH + h) * HD + d) * SEQ + sid] = f2bf(v);
        } else {
          int m = bm0 + wm * 64 + mi * 16 + quad * 4 + r;
          int n = bn0 + wn * 64 + ni * 16 + l16;
          if (mode == 0) {
            int w = n >> 9, e = n & 511;
            int h = e >> 6, d = e & 63;
            const float* bptr = (w == 0) ? bias0 : bias1;
            v += bptr[e];
            u16* optr = (w == 0) ? out0 : out1;
            int b = m >> 10, sid = m & 1023;
            optr[((size_t)(b * NH + h) * SEQ + sid) * HD + d] = f2bf(v);
          } else {
            v += bias0[n];
            v = fmaxf(v, 0.f);
            v += bf2f(resid[(size_t)m * Nstride + n]);
            out0[(size_t)m * Nstride + n] = f2bf(v);
          }
        }
      }
    }
  }
}

// ---------------- flash attention, causal ----------------------------------
// grid (qt, bh); vt is [B,H,D,S]. Tiles [64][64] unpadded, async-staged with
// XOR cg-swizzle (cg ^= row&7). sP stride 68 -> conflict-free b16 writes.
__device__ __forceinline__ void stage_tile64(u16 (*dst)[64], const u16* g, int gstride,
                                             int wave, int lane) {
  int r = lane >> 3;
  int gcg = ((lane & 7) ^ r) * 8;
#pragma unroll
  for (int c = 0; c < 2; ++c) {
    int row0 = (wave * 2 + c) * 8;
    gload16(&dst[row0][0], &g[(size_t)(row0 + r) * gstride + gcg]);
  }
}
#define RD8(T, row, cg) (*(const short8*)&T[row][(((cg) ^ ((row) & 7)) * 8)])

__global__ __launch_bounds__(256) void attn_kernel(
    const u16* __restrict__ q, const u16* __restrict__ k, const u16* __restrict__ vt,
    u16* __restrict__ o) {
  int qt = blockIdx.x;     // 0..15
  int bh = blockIdx.y;     // 0..255
  int b = bh >> 3, h = bh & 7;
  int q0 = qt * 64;
  __shared__ u16 sQ[64][64], sK[64][64], sV[64][64];
  __shared__ u16 sP[64][68];
  int tid = threadIdx.x, wave = tid >> 6, lane = tid & 63;
  int quad = lane >> 4, l16 = lane & 15;

  stage_tile64(sQ, &q[((size_t)bh * SEQ + q0) * HD], HD, wave, lane);

  floatx4 acco[4];
#pragma unroll
  for (int i = 0; i < 4; ++i) acco[i] = (floatx4){0.f, 0.f, 0.f, 0.f};
  float mrow[4], lrow[4];
#pragma unroll
  for (int r = 0; r < 4; ++r) { mrow[r] = -INFINITY; lrow[r] = 0.f; }

  for (int kt = 0; kt <= qt; ++kt) {
    int k0 = kt * 64;
    __syncthreads();   // previous iter's sK/sV reads done (and sQ at kt=0)
    stage_tile64(sK, &k[((size_t)bh * SEQ + k0) * HD], HD, wave, lane);
    stage_tile64(sV, &vt[(size_t)bh * HD * SEQ + k0], SEQ, wave, lane);
    __syncthreads();   // drains vmcnt -> staged data visible

    // S = Q @ K^T * 1/8 ; wave handles 16 q-rows x 64 keys
    floatx4 accs[4];
#pragma unroll
    for (int i = 0; i < 4; ++i) accs[i] = (floatx4){0.f, 0.f, 0.f, 0.f};
#pragma unroll
    for (int cst = 0; cst < 2; ++cst) {
      int ra = wave * 16 + l16;
      short8 aq = RD8(sQ, ra, cst * 4 + quad);
#pragma unroll
      for (int nt = 0; nt < 4; ++nt) {
        int rbk = nt * 16 + l16;
        short8 bk_ = RD8(sK, rbk, cst * 4 + quad);
        accs[nt] = __builtin_amdgcn_mfma_f32_16x16x32_bf16(aq, bk_, accs[nt], 0, 0, 0);
      }
    }

    // online softmax; only the diagonal tile needs masking
    bool diag = (kt == qt);
    int qg_base = q0 + wave * 16 + quad * 4;
    float pvv[4][4];
#pragma unroll
    for (int r = 0; r < 4; ++r) {
      float mx = -INFINITY;
#pragma unroll
      for (int nt = 0; nt < 4; ++nt) {
        float s = accs[nt][r] * 0.125f;
        if (diag) {
          int kg = k0 + nt * 16 + l16;
          if (kg > qg_base + r) s = -INFINITY;
        }
        pvv[nt][r] = s;
        mx = fmaxf(mx, s);
      }
#pragma unroll
      for (int sh = 1; sh < 16; sh <<= 1) mx = fmaxf(mx, __shfl_xor(mx, sh, 64));
      float mn = fmaxf(mrow[r], mx);
      float alpha = __expf(mrow[r] - mn);
      float sum = 0.f;
#pragma unroll
      for (int nt = 0; nt < 4; ++nt) {
        float p = __expf(pvv[nt][r] - mn);
        pvv[nt][r] = p;
        sum += p;
      }
#pragma unroll
      for (int sh = 1; sh < 16; sh <<= 1) sum += __shfl_xor(sum, sh, 64);
      lrow[r] = lrow[r] * alpha + sum;
      mrow[r] = mn;
#pragma unroll
      for (int dt = 0; dt < 4; ++dt) acco[dt][r] *= alpha;
    }

    // P (C-layout) -> LDS -> A-layout. Wave-private rows: lgkmcnt drain only.
#pragma unroll
    for (int nt = 0; nt < 4; ++nt)
#pragma unroll
      for (int r = 0; r < 4; ++r)
        sP[wave * 16 + quad * 4 + r][nt * 16 + l16] =
            (u16)(__float_as_uint(pvv[nt][r]) >> 16);   // truncate: P in [0,1]
    asm volatile("s_waitcnt lgkmcnt(0)" ::: "memory");

#pragma unroll
    for (int cst = 0; cst < 2; ++cst) {
      short8 ap = *(const short8*)&sP[wave * 16 + l16][cst * 32 + quad * 8];
#pragma unroll
      for (int dt = 0; dt < 4; ++dt) {
        int rv = dt * 16 + l16;
        short8 bv_ = RD8(sV, rv, cst * 4 + quad);
        acco[dt] = __builtin_amdgcn_mfma_f32_16x16x32_bf16(ap, bv_, acco[dt], 0, 0, 0);
      }
    }
  }

  // normalize + write [B,S,E]
#pragma unroll
  for (int dt = 0; dt < 4; ++dt)
#pragma unroll
    for (int r = 0; r < 4; ++r) {
      float ov = acco[dt][r] / lrow[r];
      int srow = q0 + wave * 16 + quad * 4 + r;
      int col = h * HD + dt * 16 + l16;
      o[((size_t)b * SEQ + srow) * EMB + col] = f2bf(ov);
    }
}

// ---------------- output head: out[m] = x[m,:] . W_out + b_out (fp32 out) ---
__global__ __launch_bounds__(256) void out_proj(const u16* __restrict__ x,
                                                const float* __restrict__ wout,
                                                const float* __restrict__ bout,
                                                float* __restrict__ out) {
  int wave = threadIdx.x >> 6, lane = threadIdx.x & 63;
  int m = blockIdx.x * 4 + wave;
  union { uint4 vv; u16 s[8]; } xv;
  xv.vv = *(const uint4*)&x[(size_t)m * EMB + lane * 8];
  float4 w0 = *(const float4*)&wout[lane * 8];
  float4 w1 = *(const float4*)&wout[lane * 8 + 4];
  float wv[8] = {w0.x, w0.y, w0.z, w0.w, w1.x, w1.y, w1.z, w1.w};
  float s = 0.f;
#pragma unroll
  for (int j = 0; j < 8; ++j) s += bf2f(xv.s[j]) * wv[j];
#pragma unroll
  for (int sh = 1; sh < 64; sh <<= 1) s += __shfl_xor(s, sh, 64);
  if (lane == 0) out[m] = s + bout[0];
}

extern "C" void kernel_launch(void* const* d_in, const int* in_sizes, int n_in,
                              void* d_out, int out_size, void* d_ws, size_t ws_size,
                              hipStream_t stream) {
  const int*   inp   = (const int*)d_in[0];
  const float* table = (const float*)d_in[1];
  const float* Wq    = (const float*)d_in[2];
  const float* bq    = (const float*)d_in[3];
  const float* Wk    = (const float*)d_in[4];
  const float* bk    = (const float*)d_in[5];
  const float* Wv    = (const float*)d_in[6];
  const float* bv    = (const float*)d_in[7];
  const float* Wo    = (const float*)d_in[8];
  const float* bo    = (const float*)d_in[9];
  const float* Wout  = (const float*)d_in[10];
  const float* bout  = (const float*)d_in[11];
  float* outp = (float*)d_out;

  char* ws = (char*)d_ws;
  const size_t SZ = (size_t)M_ROWS * EMB * 2;  // 32 MB
  u16* x      = (u16*)(ws);
  u16* qb     = (u16*)(ws + SZ);
  u16* kb     = (u16*)(ws + 2 * SZ);
  u16* vb     = (u16*)(ws + 3 * SZ);   // [B,H,D,S]
  u16* attn_b = (u16*)(ws + 4 * SZ);
  u16* WtQKV  = (u16*)(ws + 5 * SZ);
  u16* WtO    = (u16*)(ws + 5 * SZ + (size_t)NLAYER * 3 * EMB * EMB * 2);

  prep_weights<<<8192, 256, 0, stream>>>(Wq, Wk, Wv, Wo, WtQKV, WtO);
  embed_pe<<<M_ROWS, 256, 0, stream>>>(inp, table, x);

  for (int l = 0; l < NLAYER; ++l) {
    gemm_bt<<<dim3(12, 256), 256, 0, stream>>>(
        x, WtQKV + (size_t)l * 3 * EMB * EMB, EMB, /*mode=*/0,
        bq + l * EMB, bk + l * EMB, bv + l * EMB, qb, kb, vb, nullptr, 0);
    attn_kernel<<<dim3(16, 256), 256, 0, stream>>>(qb, kb, vb, attn_b);
    gemm_bt<<<dim3(4, 256), 256, 0, stream>>>(
        attn_b, WtO + (size_t)l * EMB * EMB, EMB, /*mode=*/1,
        bo + l * EMB, nullptr, nullptr, x, nullptr, nullptr, x, EMB);
  }
  out_proj<<<8192, 256, 0, stream>>>(x, Wout, bout, outp);
}

// Round 6
// 880.979 us; speedup vs baseline: 1.1338x; 1.1338x over previous
//
#include <hip/hip_runtime.h>

typedef unsigned short u16;
typedef unsigned int u32;
using short8  = __attribute__((ext_vector_type(8))) short;
using floatx4 = __attribute__((ext_vector_type(4))) float;

#define NB 32
#define SEQ 1024
#define EMB 512
#define NH 8
#define HD 64
#define NLAYER 2
#define M_ROWS (NB * SEQ)   // 32768

__device__ __forceinline__ float bf2f(u16 u) {
  union { u32 i; float f; } v; v.i = ((u32)u) << 16; return v.f;
}
__device__ __forceinline__ u16 f2bf(float f) {
  union { float f; u32 i; } v; v.f = f;
  u32 r = v.i + 0x7fffu + ((v.i >> 16) & 1u);
  return (u16)(r >> 16);
}

// async global->LDS, 16B per lane. LDS dest = wave-uniform base + lane*16.
typedef __attribute__((address_space(3))) unsigned int lds_u32_t;
typedef __attribute__((address_space(1))) const unsigned int gbl_u32_t;
__device__ __forceinline__ void gload16(void* lds, const void* g) {
  gbl_u32_t* gp = (gbl_u32_t*)(unsigned long long)g;
  lds_u32_t* lp = (lds_u32_t*)(unsigned int)(unsigned long long)lds;
  __builtin_amdgcn_global_load_lds(gp, lp, 16, 0, 0);
}

// ---------------- weight pre-transpose + fp32->bf16: W[K,N] -> Bt[N,K] ------
__global__ void prep_weights(const float* __restrict__ Wq, const float* __restrict__ Wk,
                             const float* __restrict__ Wv, const float* __restrict__ Wo,
                             u16* __restrict__ WtQKV, u16* __restrict__ WtO) {
  int idx = blockIdx.x * 256 + threadIdx.x;
  const int QKV_TOT = NLAYER * 3 * EMB * EMB;
  if (idx < QKV_TOT) {
    int l = idx / (3 * EMB * EMB);
    int rem = idx % (3 * EMB * EMB);
    int n = rem / EMB, kk = rem % EMB;
    int w = n >> 9, e = n & 511;
    const float* src = (w == 0) ? Wq : (w == 1) ? Wk : Wv;
    WtQKV[idx] = f2bf(src[((size_t)l * EMB + kk) * EMB + e]);
  } else {
    int j = idx - QKV_TOT;
    int l = j / (EMB * EMB);
    int rem = j % (EMB * EMB);
    int n = rem / EMB, kk = rem % EMB;
    WtO[j] = f2bf(Wo[((size_t)l * EMB + kk) * EMB + n]);
  }
}

// ---------------- embedding + positional encoding (fp32 in, bf16 out) -------
__global__ void embed_pe(const int* __restrict__ inp, const float* __restrict__ table,
                         u16* __restrict__ x) {
  int row = blockIdx.x;
  int tok = inp[row];
  int s = row & (SEQ - 1);
  const float negln = -9.210340371976184f / (float)EMB;
  for (int e = threadIdx.x; e < EMB; e += blockDim.x) {
    float val = table[(size_t)tok * EMB + e];
    int i = e >> 1;
    float dt = expf((float)(2 * i) * negln);
    float ang = (float)s * dt;
    float pe = (e & 1) ? cosf(ang) : sinf(ang);
    x[(size_t)row * EMB + e] = f2bf(val + pe);
  }
}

// ---------------- GEMM: C[M,N] = A[M,K] @ Bt[N,K]^T + bias ------------------
// LDS [128][32] unpadded (global_load_lds). Swizzle: chunk c of row R stored
// at slot c ^ ((R>>1)&3). Fragment b128 reads land 2-way per bank (free).
// mode 0: N=1536. Q,K -> [B,H,S,D]; V (bn0>=1024): operand-swapped MFMA,
//         C transposed in regs -> [B,H,D,S] stores sid-contiguous.
// mode 1: N=512,  x = x + relu(C + bias)   (in place, out0 == resid)
#define BK 32

__global__ __launch_bounds__(256) void gemm_bt(
    const u16* __restrict__ A, const u16* __restrict__ Bt, int K, int mode,
    const float* bias0, const float* bias1, const float* bias2,
    u16* out0, u16* out1, u16* out2, const u16* resid, int Nstride) {
  __shared__ u16 sA[128][BK];
  __shared__ u16 sB[128][BK];
  int tid = threadIdx.x;
  int wave = tid >> 6, lane = tid & 63;
  int quad = lane >> 4, l16 = lane & 15;
  int wm = wave >> 1, wn = wave & 1;
  int bn0 = blockIdx.x * 128, bm0 = blockIdx.y * 128;
  bool vswap = (mode == 0) && (bn0 >= 1024);

  floatx4 acc[4][4];
#pragma unroll
  for (int i = 0; i < 4; ++i)
#pragma unroll
    for (int j = 0; j < 4; ++j) acc[i][j] = (floatx4){0.f, 0.f, 0.f, 0.f};

  int rb = wave * 32;                         // wave stages rows rb..rb+31
  int lrow = lane >> 2;                       // 0..15
  int gcg = ((lane & 3) ^ ((lane >> 3) & 3)) * 8;  // fetch chunk for slot lane&3
  int rsl = (quad ^ ((l16 >> 1) & 3)) * 8;    // read slot holding chunk `quad`

  for (int k0 = 0; k0 < K; k0 += BK) {
#pragma unroll
    for (int c = 0; c < 2; ++c) {
      int srow = c * 16 + lrow;
      gload16(&sA[rb + c * 16][0], &A[(size_t)(bm0 + rb + srow) * K + k0 + gcg]);
      gload16(&sB[rb + c * 16][0], &Bt[(size_t)(bn0 + rb + srow) * K + k0 + gcg]);
    }
    __syncthreads();
    short8 af[4], bfr[4];
#pragma unroll
    for (int mi = 0; mi < 4; ++mi)
      af[mi] = *(const short8*)&sA[wm * 64 + mi * 16 + l16][rsl];
#pragma unroll
    for (int ni = 0; ni < 4; ++ni)
      bfr[ni] = *(const short8*)&sB[wn * 64 + ni * 16 + l16][rsl];
    if (!vswap) {
#pragma unroll
      for (int mi = 0; mi < 4; ++mi)
#pragma unroll
        for (int ni = 0; ni < 4; ++ni)
          acc[mi][ni] = __builtin_amdgcn_mfma_f32_16x16x32_bf16(af[mi], bfr[ni], acc[mi][ni], 0, 0, 0);
    } else {
#pragma unroll
      for (int mi = 0; mi < 4; ++mi)
#pragma unroll
        for (int ni = 0; ni < 4; ++ni)
          acc[mi][ni] = __builtin_amdgcn_mfma_f32_16x16x32_bf16(bfr[ni], af[mi], acc[mi][ni], 0, 0, 0);
    }
    __syncthreads();
  }

#pragma unroll
  for (int mi = 0; mi < 4; ++mi) {
#pragma unroll
    for (int ni = 0; ni < 4; ++ni) {
#pragma unroll
      for (int r = 0; r < 4; ++r) {
        float v = acc[mi][ni][r];
        if (vswap) {
          // D rows = weight rows (d), D cols = x rows (sid)
          int n = bn0 + wn * 64 + ni * 16 + quad * 4 + r;
          int m = bm0 + wm * 64 + mi * 16 + l16;
          int e = n & 511, h = (n >> 6) & 7, d = n & 63;
          int b = m >> 10, sid = m & 1023;
          v += bias2[e];
          out2[((size_t)(b * NH + h) * HD + d) * SEQ + sid] = f2bf(v);
        } else {
          int m = bm0 + wm * 64 + mi * 16 + quad * 4 + r;
          int n = bn0 + wn * 64 + ni * 16 + l16;
          if (mode == 0) {
            int w = n >> 9, e = n & 511;
            int h = e >> 6, d = e & 63;
            const float* bptr = (w == 0) ? bias0 : bias1;
            v += bptr[e];
            u16* optr = (w == 0) ? out0 : out1;
            int b = m >> 10, sid = m & 1023;
            optr[((size_t)(b * NH + h) * SEQ + sid) * HD + d] = f2bf(v);
          } else {
            v += bias0[n];
            v = fmaxf(v, 0.f);
            v += bf2f(resid[(size_t)m * Nstride + n]);
            out0[(size_t)m * Nstride + n] = f2bf(v);
          }
        }
      }
    }
  }
}

// ---------------- flash attention, causal ----------------------------------
// 1-D grid with XCD-aware mapping: all 16 qt-blocks of one bh land on ONE
// XCD consecutively -> K/V (256 KB/bh) served from that XCD's 4MB L2.
__device__ __forceinline__ void stage_tile64(u16 (*dst)[64], const u16* g, int gstride,
                                             int wave, int lane) {
  int r = lane >> 3;
  int gcg = ((lane & 7) ^ r) * 8;
#pragma unroll
  for (int c = 0; c < 2; ++c) {
    int row0 = (wave * 2 + c) * 8;
    gload16(&dst[row0][0], &g[(size_t)(row0 + r) * gstride + gcg]);
  }
}
#define RD8(T, row, cg) (*(const short8*)&T[row][(((cg) ^ ((row) & 7)) * 8)])

__global__ __launch_bounds__(256) void attn_kernel(
    const u16* __restrict__ q, const u16* __restrict__ k, const u16* __restrict__ vt,
    u16* __restrict__ o) {
  int blk = blockIdx.x;          // 0..4095
  int xcd = blk & 7, slot = blk >> 3;
  int bh = xcd * 32 + (slot >> 4);   // 32 bh's per XCD, 16 blocks each, consecutive
  int qt = slot & 15;
  int b = bh >> 3, h = bh & 7;
  int q0 = qt * 64;
  __shared__ u16 sQ[64][64], sK[64][64], sV[64][64];
  __shared__ u16 sP[64][68];
  int tid = threadIdx.x, wave = tid >> 6, lane = tid & 63;
  int quad = lane >> 4, l16 = lane & 15;

  stage_tile64(sQ, &q[((size_t)bh * SEQ + q0) * HD], HD, wave, lane);

  floatx4 acco[4];
#pragma unroll
  for (int i = 0; i < 4; ++i) acco[i] = (floatx4){0.f, 0.f, 0.f, 0.f};
  float mrow[4], lrow[4];
#pragma unroll
  for (int r = 0; r < 4; ++r) { mrow[r] = -INFINITY; lrow[r] = 0.f; }

  for (int kt = 0; kt <= qt; ++kt) {
    int k0 = kt * 64;
    __syncthreads();   // previous iter's sK/sV reads done (and sQ at kt=0)
    stage_tile64(sK, &k[((size_t)bh * SEQ + k0) * HD], HD, wave, lane);
    stage_tile64(sV, &vt[(size_t)bh * HD * SEQ + k0], SEQ, wave, lane);
    __syncthreads();   // drains vmcnt -> staged data visible

    // S = Q @ K^T * 1/8 ; wave handles 16 q-rows x 64 keys
    floatx4 accs[4];
#pragma unroll
    for (int i = 0; i < 4; ++i) accs[i] = (floatx4){0.f, 0.f, 0.f, 0.f};
#pragma unroll
    for (int cst = 0; cst < 2; ++cst) {
      int ra = wave * 16 + l16;
      short8 aq = RD8(sQ, ra, cst * 4 + quad);
#pragma unroll
      for (int nt = 0; nt < 4; ++nt) {
        int rbk = nt * 16 + l16;
        short8 bk_ = RD8(sK, rbk, cst * 4 + quad);
        accs[nt] = __builtin_amdgcn_mfma_f32_16x16x32_bf16(aq, bk_, accs[nt], 0, 0, 0);
      }
    }

    // online softmax; only the diagonal tile needs masking
    bool diag = (kt == qt);
    int qg_base = q0 + wave * 16 + quad * 4;
    float pvv[4][4];
#pragma unroll
    for (int r = 0; r < 4; ++r) {
      float mx = -INFINITY;
#pragma unroll
      for (int nt = 0; nt < 4; ++nt) {
        float s = accs[nt][r] * 0.125f;
        if (diag) {
          int kg = k0 + nt * 16 + l16;
          if (kg > qg_base + r) s = -INFINITY;
        }
        pvv[nt][r] = s;
        mx = fmaxf(mx, s);
      }
#pragma unroll
      for (int sh = 1; sh < 16; sh <<= 1) mx = fmaxf(mx, __shfl_xor(mx, sh, 64));
      float mn = fmaxf(mrow[r], mx);
      float alpha = __expf(mrow[r] - mn);
      float sum = 0.f;
#pragma unroll
      for (int nt = 0; nt < 4; ++nt) {
        float p = __expf(pvv[nt][r] - mn);
        pvv[nt][r] = p;
        sum += p;
      }
#pragma unroll
      for (int sh = 1; sh < 16; sh <<= 1) sum += __shfl_xor(sum, sh, 64);
      lrow[r] = lrow[r] * alpha + sum;
      mrow[r] = mn;
#pragma unroll
      for (int dt = 0; dt < 4; ++dt) acco[dt][r] *= alpha;
    }

    // P (C-layout) -> LDS -> A-layout. Wave-private rows: lgkmcnt drain only.
#pragma unroll
    for (int nt = 0; nt < 4; ++nt)
#pragma unroll
      for (int r = 0; r < 4; ++r)
        sP[wave * 16 + quad * 4 + r][nt * 16 + l16] =
            (u16)(__float_as_uint(pvv[nt][r]) >> 16);   // truncate: P in [0,1]
    asm volatile("s_waitcnt lgkmcnt(0)" ::: "memory");

#pragma unroll
    for (int cst = 0; cst < 2; ++cst) {
      short8 ap = *(const short8*)&sP[wave * 16 + l16][cst * 32 + quad * 8];
#pragma unroll
      for (int dt = 0; dt < 4; ++dt) {
        int rv = dt * 16 + l16;
        short8 bv_ = RD8(sV, rv, cst * 4 + quad);
        acco[dt] = __builtin_amdgcn_mfma_f32_16x16x32_bf16(ap, bv_, acco[dt], 0, 0, 0);
      }
    }
  }

  // normalize + write [B,S,E]
#pragma unroll
  for (int dt = 0; dt < 4; ++dt)
#pragma unroll
    for (int r = 0; r < 4; ++r) {
      float ov = acco[dt][r] / lrow[r];
      int srow = q0 + wave * 16 + quad * 4 + r;
      int col = h * HD + dt * 16 + l16;
      o[((size_t)b * SEQ + srow) * EMB + col] = f2bf(ov);
    }
}

// ---------------- output head: out[m] = x[m,:] . W_out + b_out (fp32 out) ---
__global__ __launch_bounds__(256) void out_proj(const u16* __restrict__ x,
                                                const float* __restrict__ wout,
                                                const float* __restrict__ bout,
                                                float* __restrict__ out) {
  int wave = threadIdx.x >> 6, lane = threadIdx.x & 63;
  int m = blockIdx.x * 4 + wave;
  union { uint4 vv; u16 s[8]; } xv;
  xv.vv = *(const uint4*)&x[(size_t)m * EMB + lane * 8];
  float4 w0 = *(const float4*)&wout[lane * 8];
  float4 w1 = *(const float4*)&wout[lane * 8 + 4];
  float wv[8] = {w0.x, w0.y, w0.z, w0.w, w1.x, w1.y, w1.z, w1.w};
  float s = 0.f;
#pragma unroll
  for (int j = 0; j < 8; ++j) s += bf2f(xv.s[j]) * wv[j];
#pragma unroll
  for (int sh = 1; sh < 64; sh <<= 1) s += __shfl_xor(s, sh, 64);
  if (lane == 0) out[m] = s + bout[0];
}

extern "C" void kernel_launch(void* const* d_in, const int* in_sizes, int n_in,
                              void* d_out, int out_size, void* d_ws, size_t ws_size,
                              hipStream_t stream) {
  const int*   inp   = (const int*)d_in[0];
  const float* table = (const float*)d_in[1];
  const float* Wq    = (const float*)d_in[2];
  const float* bq    = (const float*)d_in[3];
  const float* Wk    = (const float*)d_in[4];
  const float* bk    = (const float*)d_in[5];
  const float* Wv    = (const float*)d_in[6];
  const float* bv    = (const float*)d_in[7];
  const float* Wo    = (const float*)d_in[8];
  const float* bo    = (const float*)d_in[9];
  const float* Wout  = (const float*)d_in[10];
  const float* bout  = (const float*)d_in[11];
  float* outp = (float*)d_out;

  char* ws = (char*)d_ws;
  const size_t SZ = (size_t)M_ROWS * EMB * 2;  // 32 MB
  u16* x      = (u16*)(ws);
  u16* qb     = (u16*)(ws + SZ);
  u16* kb     = (u16*)(ws + 2 * SZ);
  u16* vb     = (u16*)(ws + 3 * SZ);   // [B,H,D,S]
  u16* attn_b = (u16*)(ws + 4 * SZ);
  u16* WtQKV  = (u16*)(ws + 5 * SZ);
  u16* WtO    = (u16*)(ws + 5 * SZ + (size_t)NLAYER * 3 * EMB * EMB * 2);

  prep_weights<<<8192, 256, 0, stream>>>(Wq, Wk, Wv, Wo, WtQKV, WtO);
  embed_pe<<<M_ROWS, 256, 0, stream>>>(inp, table, x);

  for (int l = 0; l < NLAYER; ++l) {
    gemm_bt<<<dim3(12, 256), 256, 0, stream>>>(
        x, WtQKV + (size_t)l * 3 * EMB * EMB, EMB, /*mode=*/0,
        bq + l * EMB, bk + l * EMB, bv + l * EMB, qb, kb, vb, nullptr, 0);
    attn_kernel<<<4096, 256, 0, stream>>>(qb, kb, vb, attn_b);
    gemm_bt<<<dim3(4, 256), 256, 0, stream>>>(
        attn_b, WtO + (size_t)l * EMB * EMB, EMB, /*mode=*/1,
        bo + l * EMB, nullptr, nullptr, x, nullptr, nullptr, x, EMB);
  }
  out_proj<<<8192, 256, 0, stream>>>(x, Wout, bout, outp);
}

// Round 7
// 866.023 us; speedup vs baseline: 1.1534x; 1.0173x over previous
//
#include <hip/hip_runtime.h>

typedef unsigned short u16;
typedef unsigned int u32;
using short8  = __attribute__((ext_vector_type(8))) short;
using floatx4 = __attribute__((ext_vector_type(4))) float;

#define NB 32
#define SEQ 1024
#define EMB 512
#define NH 8
#define HD 64
#define NLAYER 2
#define M_ROWS (NB * SEQ)   // 32768

__device__ __forceinline__ float bf2f(u16 u) {
  union { u32 i; float f; } v; v.i = ((u32)u) << 16; return v.f;
}
__device__ __forceinline__ u16 f2bf(float f) {
  union { float f; u32 i; } v; v.f = f;
  u32 r = v.i + 0x7fffu + ((v.i >> 16) & 1u);
  return (u16)(r >> 16);
}

// async global->LDS, 16B per lane. LDS dest = wave-uniform base + lane*16.
typedef __attribute__((address_space(3))) unsigned int lds_u32_t;
typedef __attribute__((address_space(1))) const unsigned int gbl_u32_t;
__device__ __forceinline__ void gload16(void* lds, const void* g) {
  gbl_u32_t* gp = (gbl_u32_t*)(unsigned long long)g;
  lds_u32_t* lp = (lds_u32_t*)(unsigned int)(unsigned long long)lds;
  __builtin_amdgcn_global_load_lds(gp, lp, 16, 0, 0);
}

// ---------------- weight pre-transpose + fp32->bf16: W[K,N] -> Bt[N,K] ------
__global__ void prep_weights(const float* __restrict__ Wq, const float* __restrict__ Wk,
                             const float* __restrict__ Wv, const float* __restrict__ Wo,
                             u16* __restrict__ WtQKV, u16* __restrict__ WtO) {
  int idx = blockIdx.x * 256 + threadIdx.x;
  const int QKV_TOT = NLAYER * 3 * EMB * EMB;
  if (idx < QKV_TOT) {
    int l = idx / (3 * EMB * EMB);
    int rem = idx % (3 * EMB * EMB);
    int n = rem / EMB, kk = rem % EMB;
    int w = n >> 9, e = n & 511;
    const float* src = (w == 0) ? Wq : (w == 1) ? Wk : Wv;
    WtQKV[idx] = f2bf(src[((size_t)l * EMB + kk) * EMB + e]);
  } else {
    int j = idx - QKV_TOT;
    int l = j / (EMB * EMB);
    int rem = j % (EMB * EMB);
    int n = rem / EMB, kk = rem % EMB;
    WtO[j] = f2bf(Wo[((size_t)l * EMB + kk) * EMB + n]);
  }
}

// ---------------- embedding + positional encoding (fp32 in, bf16 out) -------
__global__ void embed_pe(const int* __restrict__ inp, const float* __restrict__ table,
                         u16* __restrict__ x) {
  int row = blockIdx.x;
  int tok = inp[row];
  int s = row & (SEQ - 1);
  const float negln = -9.210340371976184f / (float)EMB;
  for (int e = threadIdx.x; e < EMB; e += blockDim.x) {
    float val = table[(size_t)tok * EMB + e];
    int i = e >> 1;
    float dt = expf((float)(2 * i) * negln);
    float ang = (float)s * dt;
    float pe = (e & 1) ? cosf(ang) : sinf(ang);
    x[(size_t)row * EMB + e] = f2bf(val + pe);
  }
}

// ---------------- GEMM: C[M,N] = A[M,K] @ Bt[N,K]^T + bias ------------------
// 1-D grid, XCD-aware: xcd = blk&7; within an XCD, all N-tiles of one M-tile
// are consecutive -> A-tile fetched into exactly one XCD L2 (no replication).
// LDS [128][32] unpadded; chunk c of row R at slot c^((R>>1)&3) (2-way=free).
// mode 0: N=1536 (NT=12). Q,K -> [B,H,S,D]; V (bn0>=1024): operand-swapped
//         MFMA -> C transposed in regs -> [B,H,D,S] stores sid-contiguous.
// mode 1: N=512 (NT=4),  x = x + relu(C + bias)  (in place, out0 == resid)
#define BK 32

__global__ __launch_bounds__(256) void gemm_bt(
    const u16* __restrict__ A, const u16* __restrict__ Bt, int K, int mode,
    const float* bias0, const float* bias1, const float* bias2,
    u16* out0, u16* out1, u16* out2, const u16* resid, int Nstride) {
  __shared__ u16 sA[128][BK];
  __shared__ u16 sB[128][BK];
  int tid = threadIdx.x;
  int wave = tid >> 6, lane = tid & 63;
  int quad = lane >> 4, l16 = lane & 15;
  int wm = wave >> 1, wn = wave & 1;

  int NT = (mode == 0) ? 12 : 4;          // N-tiles per M-tile
  int blk = blockIdx.x;
  int xcd = blk & 7, slot = blk >> 3;
  int mtl = slot / NT, ntl = slot % NT;   // 32 M-tiles per XCD, N-tiles inner
  int bm0 = (xcd * 32 + mtl) * 128;
  int bn0 = ntl * 128;
  bool vswap = (mode == 0) && (bn0 >= 1024);

  floatx4 acc[4][4];
#pragma unroll
  for (int i = 0; i < 4; ++i)
#pragma unroll
    for (int j = 0; j < 4; ++j) acc[i][j] = (floatx4){0.f, 0.f, 0.f, 0.f};

  int rb = wave * 32;                         // wave stages rows rb..rb+31
  int lrow = lane >> 2;                       // 0..15
  int gcg = ((lane & 3) ^ ((lane >> 3) & 3)) * 8;  // fetch chunk for slot lane&3
  int rsl = (quad ^ ((l16 >> 1) & 3)) * 8;    // read slot holding chunk `quad`

  for (int k0 = 0; k0 < K; k0 += BK) {
#pragma unroll
    for (int c = 0; c < 2; ++c) {
      int srow = c * 16 + lrow;
      gload16(&sA[rb + c * 16][0], &A[(size_t)(bm0 + rb + srow) * K + k0 + gcg]);
      gload16(&sB[rb + c * 16][0], &Bt[(size_t)(bn0 + rb + srow) * K + k0 + gcg]);
    }
    __syncthreads();
    short8 af[4], bfr[4];
#pragma unroll
    for (int mi = 0; mi < 4; ++mi)
      af[mi] = *(const short8*)&sA[wm * 64 + mi * 16 + l16][rsl];
#pragma unroll
    for (int ni = 0; ni < 4; ++ni)
      bfr[ni] = *(const short8*)&sB[wn * 64 + ni * 16 + l16][rsl];
    if (!vswap) {
#pragma unroll
      for (int mi = 0; mi < 4; ++mi)
#pragma unroll
        for (int ni = 0; ni < 4; ++ni)
          acc[mi][ni] = __builtin_amdgcn_mfma_f32_16x16x32_bf16(af[mi], bfr[ni], acc[mi][ni], 0, 0, 0);
    } else {
#pragma unroll
      for (int mi = 0; mi < 4; ++mi)
#pragma unroll
        for (int ni = 0; ni < 4; ++ni)
          acc[mi][ni] = __builtin_amdgcn_mfma_f32_16x16x32_bf16(bfr[ni], af[mi], acc[mi][ni], 0, 0, 0);
    }
    __syncthreads();
  }

#pragma unroll
  for (int mi = 0; mi < 4; ++mi) {
#pragma unroll
    for (int ni = 0; ni < 4; ++ni) {
#pragma unroll
      for (int r = 0; r < 4; ++r) {
        float v = acc[mi][ni][r];
        if (vswap) {
          // D rows = weight rows (d), D cols = x rows (sid)
          int n = bn0 + wn * 64 + ni * 16 + quad * 4 + r;
          int m = bm0 + wm * 64 + mi * 16 + l16;
          int e = n & 511, h = (n >> 6) & 7, d = n & 63;
          int b = m >> 10, sid = m & 1023;
          v += bias2[e];
          out2[((size_t)(b * NH + h) * HD + d) * SEQ + sid] = f2bf(v);
        } else {
          int m = bm0 + wm * 64 + mi * 16 + quad * 4 + r;
          int n = bn0 + wn * 64 + ni * 16 + l16;
          if (mode == 0) {
            int w = n >> 9, e = n & 511;
            int h = e >> 6, d = e & 63;
            const float* bptr = (w == 0) ? bias0 : bias1;
            v += bptr[e];
            u16* optr = (w == 0) ? out0 : out1;
            int b = m >> 10, sid = m & 1023;
            optr[((size_t)(b * NH + h) * SEQ + sid) * HD + d] = f2bf(v);
          } else {
            v += bias0[n];
            v = fmaxf(v, 0.f);
            v += bf2f(resid[(size_t)m * Nstride + n]);
            out0[(size_t)m * Nstride + n] = f2bf(v);
          }
        }
      }
    }
  }
}

// ---------------- flash attention, causal ----------------------------------
// 1-D grid with XCD-aware mapping: all 16 qt-blocks of one bh land on ONE
// XCD consecutively -> K/V (256 KB/bh) served from that XCD's 4MB L2.
__device__ __forceinline__ void stage_tile64(u16 (*dst)[64], const u16* g, int gstride,
                                             int wave, int lane) {
  int r = lane >> 3;
  int gcg = ((lane & 7) ^ r) * 8;
#pragma unroll
  for (int c = 0; c < 2; ++c) {
    int row0 = (wave * 2 + c) * 8;
    gload16(&dst[row0][0], &g[(size_t)(row0 + r) * gstride + gcg]);
  }
}
#define RD8(T, row, cg) (*(const short8*)&T[row][(((cg) ^ ((row) & 7)) * 8)])

__global__ __launch_bounds__(256) void attn_kernel(
    const u16* __restrict__ q, const u16* __restrict__ k, const u16* __restrict__ vt,
    u16* __restrict__ o) {
  int blk = blockIdx.x;          // 0..4095
  int xcd = blk & 7, slot = blk >> 3;
  int bh = xcd * 32 + (slot >> 4);   // 32 bh's per XCD, 16 blocks each, consecutive
  int qt = slot & 15;
  int b = bh >> 3, h = bh & 7;
  int q0 = qt * 64;
  __shared__ u16 sQ[64][64], sK[64][64], sV[64][64];
  __shared__ u16 sP[64][68];
  int tid = threadIdx.x, wave = tid >> 6, lane = tid & 63;
  int quad = lane >> 4, l16 = lane & 15;

  stage_tile64(sQ, &q[((size_t)bh * SEQ + q0) * HD], HD, wave, lane);

  floatx4 acco[4];
#pragma unroll
  for (int i = 0; i < 4; ++i) acco[i] = (floatx4){0.f, 0.f, 0.f, 0.f};
  float mrow[4], lrow[4];
#pragma unroll
  for (int r = 0; r < 4; ++r) { mrow[r] = -INFINITY; lrow[r] = 0.f; }

  for (int kt = 0; kt <= qt; ++kt) {
    int k0 = kt * 64;
    __syncthreads();   // previous iter's sK/sV reads done (and sQ at kt=0)
    stage_tile64(sK, &k[((size_t)bh * SEQ + k0) * HD], HD, wave, lane);
    stage_tile64(sV, &vt[(size_t)bh * HD * SEQ + k0], SEQ, wave, lane);
    __syncthreads();   // drains vmcnt -> staged data visible

    // S = Q @ K^T * 1/8 ; wave handles 16 q-rows x 64 keys
    floatx4 accs[4];
#pragma unroll
    for (int i = 0; i < 4; ++i) accs[i] = (floatx4){0.f, 0.f, 0.f, 0.f};
#pragma unroll
    for (int cst = 0; cst < 2; ++cst) {
      int ra = wave * 16 + l16;
      short8 aq = RD8(sQ, ra, cst * 4 + quad);
#pragma unroll
      for (int nt = 0; nt < 4; ++nt) {
        int rbk = nt * 16 + l16;
        short8 bk_ = RD8(sK, rbk, cst * 4 + quad);
        accs[nt] = __builtin_amdgcn_mfma_f32_16x16x32_bf16(aq, bk_, accs[nt], 0, 0, 0);
      }
    }

    // online softmax; only the diagonal tile needs masking
    bool diag = (kt == qt);
    int qg_base = q0 + wave * 16 + quad * 4;
    float pvv[4][4];
#pragma unroll
    for (int r = 0; r < 4; ++r) {
      float mx = -INFINITY;
#pragma unroll
      for (int nt = 0; nt < 4; ++nt) {
        float s = accs[nt][r] * 0.125f;
        if (diag) {
          int kg = k0 + nt * 16 + l16;
          if (kg > qg_base + r) s = -INFINITY;
        }
        pvv[nt][r] = s;
        mx = fmaxf(mx, s);
      }
#pragma unroll
      for (int sh = 1; sh < 16; sh <<= 1) mx = fmaxf(mx, __shfl_xor(mx, sh, 64));
      float mn = fmaxf(mrow[r], mx);
      float alpha = __expf(mrow[r] - mn);
      float sum = 0.f;
#pragma unroll
      for (int nt = 0; nt < 4; ++nt) {
        float p = __expf(pvv[nt][r] - mn);
        pvv[nt][r] = p;
        sum += p;
      }
#pragma unroll
      for (int sh = 1; sh < 16; sh <<= 1) sum += __shfl_xor(sum, sh, 64);
      lrow[r] = lrow[r] * alpha + sum;
      mrow[r] = mn;
#pragma unroll
      for (int dt = 0; dt < 4; ++dt) acco[dt][r] *= alpha;
    }

    // P (C-layout) -> LDS -> A-layout. Wave-private rows: lgkmcnt drain only.
#pragma unroll
    for (int nt = 0; nt < 4; ++nt)
#pragma unroll
      for (int r = 0; r < 4; ++r)
        sP[wave * 16 + quad * 4 + r][nt * 16 + l16] =
            (u16)(__float_as_uint(pvv[nt][r]) >> 16);   // truncate: P in [0,1]
    asm volatile("s_waitcnt lgkmcnt(0)" ::: "memory");

#pragma unroll
    for (int cst = 0; cst < 2; ++cst) {
      short8 ap = *(const short8*)&sP[wave * 16 + l16][cst * 32 + quad * 8];
#pragma unroll
      for (int dt = 0; dt < 4; ++dt) {
        int rv = dt * 16 + l16;
        short8 bv_ = RD8(sV, rv, cst * 4 + quad);
        acco[dt] = __builtin_amdgcn_mfma_f32_16x16x32_bf16(ap, bv_, acco[dt], 0, 0, 0);
      }
    }
  }

  // normalize + write [B,S,E]
#pragma unroll
  for (int dt = 0; dt < 4; ++dt)
#pragma unroll
    for (int r = 0; r < 4; ++r) {
      float ov = acco[dt][r] / lrow[r];
      int srow = q0 + wave * 16 + quad * 4 + r;
      int col = h * HD + dt * 16 + l16;
      o[((size_t)b * SEQ + srow) * EMB + col] = f2bf(ov);
    }
}

// ---------------- output head: out[m] = x[m,:] . W_out + b_out (fp32 out) ---
__global__ __launch_bounds__(256) void out_proj(const u16* __restrict__ x,
                                                const float* __restrict__ wout,
                                                const float* __restrict__ bout,
                                                float* __restrict__ out) {
  int wave = threadIdx.x >> 6, lane = threadIdx.x & 63;
  int m = blockIdx.x * 4 + wave;
  union { uint4 vv; u16 s[8]; } xv;
  xv.vv = *(const uint4*)&x[(size_t)m * EMB + lane * 8];
  float4 w0 = *(const float4*)&wout[lane * 8];
  float4 w1 = *(const float4*)&wout[lane * 8 + 4];
  float wv[8] = {w0.x, w0.y, w0.z, w0.w, w1.x, w1.y, w1.z, w1.w};
  float s = 0.f;
#pragma unroll
  for (int j = 0; j < 8; ++j) s += bf2f(xv.s[j]) * wv[j];
#pragma unroll
  for (int sh = 1; sh < 64; sh <<= 1) s += __shfl_xor(s, sh, 64);
  if (lane == 0) out[m] = s + bout[0];
}

extern "C" void kernel_launch(void* const* d_in, const int* in_sizes, int n_in,
                              void* d_out, int out_size, void* d_ws, size_t ws_size,
                              hipStream_t stream) {
  const int*   inp   = (const int*)d_in[0];
  const float* table = (const float*)d_in[1];
  const float* Wq    = (const float*)d_in[2];
  const float* bq    = (const float*)d_in[3];
  const float* Wk    = (const float*)d_in[4];
  const float* bk    = (const float*)d_in[5];
  const float* Wv    = (const float*)d_in[6];
  const float* bv    = (const float*)d_in[7];
  const float* Wo    = (const float*)d_in[8];
  const float* bo    = (const float*)d_in[9];
  const float* Wout  = (const float*)d_in[10];
  const float* bout  = (const float*)d_in[11];
  float* outp = (float*)d_out;

  char* ws = (char*)d_ws;
  const size_t SZ = (size_t)M_ROWS * EMB * 2;  // 32 MB
  u16* x      = (u16*)(ws);
  u16* qb     = (u16*)(ws + SZ);
  u16* kb     = (u16*)(ws + 2 * SZ);
  u16* vb     = (u16*)(ws + 3 * SZ);   // [B,H,D,S]
  u16* attn_b = (u16*)(ws + 4 * SZ);
  u16* WtQKV  = (u16*)(ws + 5 * SZ);
  u16* WtO    = (u16*)(ws + 5 * SZ + (size_t)NLAYER * 3 * EMB * EMB * 2);

  prep_weights<<<8192, 256, 0, stream>>>(Wq, Wk, Wv, Wo, WtQKV, WtO);
  embed_pe<<<M_ROWS, 256, 0, stream>>>(inp, table, x);

  for (int l = 0; l < NLAYER; ++l) {
    gemm_bt<<<3072, 256, 0, stream>>>(
        x, WtQKV + (size_t)l * 3 * EMB * EMB, EMB, /*mode=*/0,
        bq + l * EMB, bk + l * EMB, bv + l * EMB, qb, kb, vb, nullptr, 0);
    attn_kernel<<<4096, 256, 0, stream>>>(qb, kb, vb, attn_b);
    gemm_bt<<<1024, 256, 0, stream>>>(
        attn_b, WtO + (size_t)l * EMB * EMB, EMB, /*mode=*/1,
        bo + l * EMB, nullptr, nullptr, x, nullptr, nullptr, x, EMB);
  }
  out_proj<<<8192, 256, 0, stream>>>(x, Wout, bout, outp);
}

// Round 8
// 820.651 us; speedup vs baseline: 1.2171x; 1.0553x over previous
//
#include <hip/hip_runtime.h>

typedef unsigned short u16;
typedef unsigned int u32;
using short8  = __attribute__((ext_vector_type(8))) short;
using floatx4 = __attribute__((ext_vector_type(4))) float;

#define NB 32
#define SEQ 1024
#define EMB 512
#define NH 8
#define HD 64
#define NLAYER 2
#define M_ROWS (NB * SEQ)   // 32768

__device__ __forceinline__ float bf2f(u16 u) {
  union { u32 i; float f; } v; v.i = ((u32)u) << 16; return v.f;
}
__device__ __forceinline__ u16 f2bf(float f) {
  union { float f; u32 i; } v; v.f = f;
  u32 r = v.i + 0x7fffu + ((v.i >> 16) & 1u);
  return (u16)(r >> 16);
}

// async global->LDS, 16B per lane. LDS dest = wave-uniform base + lane*16.
typedef __attribute__((address_space(3))) unsigned int lds_u32_t;
typedef __attribute__((address_space(1))) const unsigned int gbl_u32_t;
__device__ __forceinline__ void gload16(void* lds, const void* g) {
  gbl_u32_t* gp = (gbl_u32_t*)(unsigned long long)g;
  lds_u32_t* lp = (lds_u32_t*)(unsigned int)(unsigned long long)lds;
  __builtin_amdgcn_global_load_lds(gp, lp, 16, 0, 0);
}

// ---------------- weight pre-transpose + fp32->bf16: W[K,N] -> Bt[N,K] ------
__global__ void prep_weights(const float* __restrict__ Wq, const float* __restrict__ Wk,
                             const float* __restrict__ Wv, const float* __restrict__ Wo,
                             u16* __restrict__ WtQKV, u16* __restrict__ WtO) {
  int idx = blockIdx.x * 256 + threadIdx.x;
  const int QKV_TOT = NLAYER * 3 * EMB * EMB;
  if (idx < QKV_TOT) {
    int l = idx / (3 * EMB * EMB);
    int rem = idx % (3 * EMB * EMB);
    int n = rem / EMB, kk = rem % EMB;
    int w = n >> 9, e = n & 511;
    const float* src = (w == 0) ? Wq : (w == 1) ? Wk : Wv;
    WtQKV[idx] = f2bf(src[((size_t)l * EMB + kk) * EMB + e]);
  } else {
    int j = idx - QKV_TOT;
    int l = j / (EMB * EMB);
    int rem = j % (EMB * EMB);
    int n = rem / EMB, kk = rem % EMB;
    WtO[j] = f2bf(Wo[((size_t)l * EMB + kk) * EMB + n]);
  }
}

// ---------------- embedding + positional encoding (fp32 in, bf16 out) -------
__global__ void embed_pe(const int* __restrict__ inp, const float* __restrict__ table,
                         u16* __restrict__ x) {
  int row = blockIdx.x;
  int tok = inp[row];
  int s = row & (SEQ - 1);
  const float negln = -9.210340371976184f / (float)EMB;
  for (int e = threadIdx.x; e < EMB; e += blockDim.x) {
    float val = table[(size_t)tok * EMB + e];
    int i = e >> 1;
    float dt = expf((float)(2 * i) * negln);
    float ang = (float)s * dt;
    float pe = (e & 1) ? cosf(ang) : sinf(ang);
    x[(size_t)row * EMB + e] = f2bf(val + pe);
  }
}

// ---------------- GEMM: C[M,N] = A[M,K] @ Bt[N,K]^T + bias ------------------
// XCD-aware 1-D grid (A-tile pinned to one XCD L2). Double-buffered K-loop:
// prefetch next tile, s_waitcnt vmcnt(4) waits only the current buffer's 4
// loads (prefetch stays in flight), raw s_barrier (no compiler vmcnt(0)
// drain). Swizzle: chunk c of row R at slot c^((R>>1)&3) -> 2-way (free).
// mode 0: N=1536 (NT=12). Q,K -> [B,H,S,D]; V (bn0>=1024): operand-swapped
//         MFMA -> C transposed in regs -> [B,H,D,S] stores sid-contiguous.
// mode 1: N=512 (NT=4),  x = x + relu(C + bias)  (in place, out0 == resid)
#define BK 32

__global__ __launch_bounds__(256) void gemm_bt(
    const u16* __restrict__ A, const u16* __restrict__ Bt, int K, int mode,
    const float* bias0, const float* bias1, const float* bias2,
    u16* out0, u16* out1, u16* out2, const u16* resid, int Nstride) {
  __shared__ u16 sA[2][128][BK];
  __shared__ u16 sB[2][128][BK];
  int tid = threadIdx.x;
  int wave = tid >> 6, lane = tid & 63;
  int quad = lane >> 4, l16 = lane & 15;
  int wm = wave >> 1, wn = wave & 1;

  int NT = (mode == 0) ? 12 : 4;          // N-tiles per M-tile
  int blk = blockIdx.x;
  int xcd = blk & 7, slot = blk >> 3;
  int mtl = slot / NT, ntl = slot % NT;   // 32 M-tiles per XCD, N-tiles inner
  int bm0 = (xcd * 32 + mtl) * 128;
  int bn0 = ntl * 128;
  bool vswap = (mode == 0) && (bn0 >= 1024);

  floatx4 acc[4][4];
#pragma unroll
  for (int i = 0; i < 4; ++i)
#pragma unroll
    for (int j = 0; j < 4; ++j) acc[i][j] = (floatx4){0.f, 0.f, 0.f, 0.f};

  int rb = wave * 32;                         // wave stages rows rb..rb+31
  int lrow = lane >> 2;                       // 0..15
  int gcg = ((lane & 3) ^ ((lane >> 3) & 3)) * 8;  // fetch chunk for slot lane&3
  int rsl = (quad ^ ((l16 >> 1) & 3)) * 8;    // read slot holding chunk `quad`

  const u16* Arow0 = &A[(size_t)(bm0 + rb + lrow) * K + gcg];
  const u16* Arow1 = &A[(size_t)(bm0 + rb + 16 + lrow) * K + gcg];
  const u16* Brow0 = &Bt[(size_t)(bn0 + rb + lrow) * K + gcg];
  const u16* Brow1 = &Bt[(size_t)(bn0 + rb + 16 + lrow) * K + gcg];

  // prologue: stage k-tile 0 into buffer 0 (4 loads per wave)
  gload16(&sA[0][rb][0],      Arow0);
  gload16(&sA[0][rb + 16][0], Arow1);
  gload16(&sB[0][rb][0],      Brow0);
  gload16(&sB[0][rb + 16][0], Brow1);

  const int niter = K / BK;
  int ibuf = 0;
  for (int it = 0; it < niter; ++it) {
    if (it + 1 < niter) {
      int k1 = (it + 1) * BK;
      int nb = ibuf ^ 1;
      gload16(&sA[nb][rb][0],      Arow0 + k1);
      gload16(&sA[nb][rb + 16][0], Arow1 + k1);
      gload16(&sB[nb][rb][0],      Brow0 + k1);
      gload16(&sB[nb][rb + 16][0], Brow1 + k1);
      asm volatile("s_waitcnt vmcnt(4)" ::: "memory");  // current buf's 4 done
    } else {
      asm volatile("s_waitcnt vmcnt(0)" ::: "memory");
    }
    asm volatile("s_barrier" ::: "memory");             // buf ready for all

    short8 af[4], bfr[4];
#pragma unroll
    for (int mi = 0; mi < 4; ++mi)
      af[mi] = *(const short8*)&sA[ibuf][wm * 64 + mi * 16 + l16][rsl];
#pragma unroll
    for (int ni = 0; ni < 4; ++ni)
      bfr[ni] = *(const short8*)&sB[ibuf][wn * 64 + ni * 16 + l16][rsl];
    if (!vswap) {
#pragma unroll
      for (int mi = 0; mi < 4; ++mi)
#pragma unroll
        for (int ni = 0; ni < 4; ++ni)
          acc[mi][ni] = __builtin_amdgcn_mfma_f32_16x16x32_bf16(af[mi], bfr[ni], acc[mi][ni], 0, 0, 0);
    } else {
#pragma unroll
      for (int mi = 0; mi < 4; ++mi)
#pragma unroll
        for (int ni = 0; ni < 4; ++ni)
          acc[mi][ni] = __builtin_amdgcn_mfma_f32_16x16x32_bf16(bfr[ni], af[mi], acc[mi][ni], 0, 0, 0);
    }
    asm volatile("s_barrier" ::: "memory");             // reads done before overwrite
    ibuf ^= 1;
  }

#pragma unroll
  for (int mi = 0; mi < 4; ++mi) {
#pragma unroll
    for (int ni = 0; ni < 4; ++ni) {
#pragma unroll
      for (int r = 0; r < 4; ++r) {
        float v = acc[mi][ni][r];
        if (vswap) {
          // D rows = weight rows (d), D cols = x rows (sid)
          int n = bn0 + wn * 64 + ni * 16 + quad * 4 + r;
          int m = bm0 + wm * 64 + mi * 16 + l16;
          int e = n & 511, h = (n >> 6) & 7, d = n & 63;
          int b = m >> 10, sid = m & 1023;
          v += bias2[e];
          out2[((size_t)(b * NH + h) * HD + d) * SEQ + sid] = f2bf(v);
        } else {
          int m = bm0 + wm * 64 + mi * 16 + quad * 4 + r;
          int n = bn0 + wn * 64 + ni * 16 + l16;
          if (mode == 0) {
            int w = n >> 9, e = n & 511;
            int h = e >> 6, d = e & 63;
            const float* bptr = (w == 0) ? bias0 : bias1;
            v += bptr[e];
            u16* optr = (w == 0) ? out0 : out1;
            int b = m >> 10, sid = m & 1023;
            optr[((size_t)(b * NH + h) * SEQ + sid) * HD + d] = f2bf(v);
          } else {
            v += bias0[n];
            v = fmaxf(v, 0.f);
            v += bf2f(resid[(size_t)m * Nstride + n]);
            out0[(size_t)m * Nstride + n] = f2bf(v);
          }
        }
      }
    }
  }
}

// ---------------- flash attention, causal ----------------------------------
// 1-D grid with XCD-aware mapping: all 16 qt-blocks of one bh land on ONE
// XCD consecutively -> K/V (256 KB/bh) served from that XCD's 4MB L2.
__device__ __forceinline__ void stage_tile64(u16 (*dst)[64], const u16* g, int gstride,
                                             int wave, int lane) {
  int r = lane >> 3;
  int gcg = ((lane & 7) ^ r) * 8;
#pragma unroll
  for (int c = 0; c < 2; ++c) {
    int row0 = (wave * 2 + c) * 8;
    gload16(&dst[row0][0], &g[(size_t)(row0 + r) * gstride + gcg]);
  }
}
#define RD8(T, row, cg) (*(const short8*)&T[row][(((cg) ^ ((row) & 7)) * 8)])

__global__ __launch_bounds__(256) void attn_kernel(
    const u16* __restrict__ q, const u16* __restrict__ k, const u16* __restrict__ vt,
    u16* __restrict__ o) {
  int blk = blockIdx.x;          // 0..4095
  int xcd = blk & 7, slot = blk >> 3;
  int bh = xcd * 32 + (slot >> 4);   // 32 bh's per XCD, 16 blocks each, consecutive
  int qt = slot & 15;
  int b = bh >> 3, h = bh & 7;
  int q0 = qt * 64;
  __shared__ u16 sQ[64][64], sK[64][64], sV[64][64];
  __shared__ u16 sP[64][68];
  int tid = threadIdx.x, wave = tid >> 6, lane = tid & 63;
  int quad = lane >> 4, l16 = lane & 15;

  stage_tile64(sQ, &q[((size_t)bh * SEQ + q0) * HD], HD, wave, lane);

  floatx4 acco[4];
#pragma unroll
  for (int i = 0; i < 4; ++i) acco[i] = (floatx4){0.f, 0.f, 0.f, 0.f};
  float mrow[4], lrow[4];
#pragma unroll
  for (int r = 0; r < 4; ++r) { mrow[r] = -INFINITY; lrow[r] = 0.f; }

  for (int kt = 0; kt <= qt; ++kt) {
    int k0 = kt * 64;
    __syncthreads();   // previous iter's sK/sV reads done (and sQ at kt=0)
    stage_tile64(sK, &k[((size_t)bh * SEQ + k0) * HD], HD, wave, lane);
    stage_tile64(sV, &vt[(size_t)bh * HD * SEQ + k0], SEQ, wave, lane);
    __syncthreads();   // drains vmcnt -> staged data visible

    // S = Q @ K^T * 1/8 ; wave handles 16 q-rows x 64 keys
    floatx4 accs[4];
#pragma unroll
    for (int i = 0; i < 4; ++i) accs[i] = (floatx4){0.f, 0.f, 0.f, 0.f};
#pragma unroll
    for (int cst = 0; cst < 2; ++cst) {
      int ra = wave * 16 + l16;
      short8 aq = RD8(sQ, ra, cst * 4 + quad);
#pragma unroll
      for (int nt = 0; nt < 4; ++nt) {
        int rbk = nt * 16 + l16;
        short8 bk_ = RD8(sK, rbk, cst * 4 + quad);
        accs[nt] = __builtin_amdgcn_mfma_f32_16x16x32_bf16(aq, bk_, accs[nt], 0, 0, 0);
      }
    }

    // online softmax; only the diagonal tile needs masking
    bool diag = (kt == qt);
    int qg_base = q0 + wave * 16 + quad * 4;
    float pvv[4][4];
#pragma unroll
    for (int r = 0; r < 4; ++r) {
      float mx = -INFINITY;
#pragma unroll
      for (int nt = 0; nt < 4; ++nt) {
        float s = accs[nt][r] * 0.125f;
        if (diag) {
          int kg = k0 + nt * 16 + l16;
          if (kg > qg_base + r) s = -INFINITY;
        }
        pvv[nt][r] = s;
        mx = fmaxf(mx, s);
      }
#pragma unroll
      for (int sh = 1; sh < 16; sh <<= 1) mx = fmaxf(mx, __shfl_xor(mx, sh, 64));
      float mn = fmaxf(mrow[r], mx);
      float alpha = __expf(mrow[r] - mn);
      float sum = 0.f;
#pragma unroll
      for (int nt = 0; nt < 4; ++nt) {
        float p = __expf(pvv[nt][r] - mn);
        pvv[nt][r] = p;
        sum += p;
      }
#pragma unroll
      for (int sh = 1; sh < 16; sh <<= 1) sum += __shfl_xor(sum, sh, 64);
      lrow[r] = lrow[r] * alpha + sum;
      mrow[r] = mn;
#pragma unroll
      for (int dt = 0; dt < 4; ++dt) acco[dt][r] *= alpha;
    }

    // P (C-layout) -> LDS -> A-layout. Wave-private rows: lgkmcnt drain only.
#pragma unroll
    for (int nt = 0; nt < 4; ++nt)
#pragma unroll
      for (int r = 0; r < 4; ++r)
        sP[wave * 16 + quad * 4 + r][nt * 16 + l16] =
            (u16)(__float_as_uint(pvv[nt][r]) >> 16);   // truncate: P in [0,1]
    asm volatile("s_waitcnt lgkmcnt(0)" ::: "memory");

#pragma unroll
    for (int cst = 0; cst < 2; ++cst) {
      short8 ap = *(const short8*)&sP[wave * 16 + l16][cst * 32 + quad * 8];
#pragma unroll
      for (int dt = 0; dt < 4; ++dt) {
        int rv = dt * 16 + l16;
        short8 bv_ = RD8(sV, rv, cst * 4 + quad);
        acco[dt] = __builtin_amdgcn_mfma_f32_16x16x32_bf16(ap, bv_, acco[dt], 0, 0, 0);
      }
    }
  }

  // normalize + write [B,S,E]
#pragma unroll
  for (int dt = 0; dt < 4; ++dt)
#pragma unroll
    for (int r = 0; r < 4; ++r) {
      float ov = acco[dt][r] / lrow[r];
      int srow = q0 + wave * 16 + quad * 4 + r;
      int col = h * HD + dt * 16 + l16;
      o[((size_t)b * SEQ + srow) * EMB + col] = f2bf(ov);
    }
}

// ---------------- output head: out[m] = x[m,:] . W_out + b_out (fp32 out) ---
__global__ __launch_bounds__(256) void out_proj(const u16* __restrict__ x,
                                                const float* __restrict__ wout,
                                                const float* __restrict__ bout,
                                                float* __restrict__ out) {
  int wave = threadIdx.x >> 6, lane = threadIdx.x & 63;
  int m = blockIdx.x * 4 + wave;
  union { uint4 vv; u16 s[8]; } xv;
  xv.vv = *(const uint4*)&x[(size_t)m * EMB + lane * 8];
  float4 w0 = *(const float4*)&wout[lane * 8];
  float4 w1 = *(const float4*)&wout[lane * 8 + 4];
  float wv[8] = {w0.x, w0.y, w0.z, w0.w, w1.x, w1.y, w1.z, w1.w};
  float s = 0.f;
#pragma unroll
  for (int j = 0; j < 8; ++j) s += bf2f(xv.s[j]) * wv[j];
#pragma unroll
  for (int sh = 1; sh < 64; sh <<= 1) s += __shfl_xor(s, sh, 64);
  if (lane == 0) out[m] = s + bout[0];
}

extern "C" void kernel_launch(void* const* d_in, const int* in_sizes, int n_in,
                              void* d_out, int out_size, void* d_ws, size_t ws_size,
                              hipStream_t stream) {
  const int*   inp   = (const int*)d_in[0];
  const float* table = (const float*)d_in[1];
  const float* Wq    = (const float*)d_in[2];
  const float* bq    = (const float*)d_in[3];
  const float* Wk    = (const float*)d_in[4];
  const float* bk    = (const float*)d_in[5];
  const float* Wv    = (const float*)d_in[6];
  const float* bv    = (const float*)d_in[7];
  const float* Wo    = (const float*)d_in[8];
  const float* bo    = (const float*)d_in[9];
  const float* Wout  = (const float*)d_in[10];
  const float* bout  = (const float*)d_in[11];
  float* outp = (float*)d_out;

  char* ws = (char*)d_ws;
  const size_t SZ = (size_t)M_ROWS * EMB * 2;  // 32 MB
  u16* x      = (u16*)(ws);
  u16* qb     = (u16*)(ws + SZ);
  u16* kb     = (u16*)(ws + 2 * SZ);
  u16* vb     = (u16*)(ws + 3 * SZ);   // [B,H,D,S]
  u16* attn_b = (u16*)(ws + 4 * SZ);
  u16* WtQKV  = (u16*)(ws + 5 * SZ);
  u16* WtO    = (u16*)(ws + 5 * SZ + (size_t)NLAYER * 3 * EMB * EMB * 2);

  prep_weights<<<8192, 256, 0, stream>>>(Wq, Wk, Wv, Wo, WtQKV, WtO);
  embed_pe<<<M_ROWS, 256, 0, stream>>>(inp, table, x);

  for (int l = 0; l < NLAYER; ++l) {
    gemm_bt<<<3072, 256, 0, stream>>>(
        x, WtQKV + (size_t)l * 3 * EMB * EMB, EMB, /*mode=*/0,
        bq + l * EMB, bk + l * EMB, bv + l * EMB, qb, kb, vb, nullptr, 0);
    attn_kernel<<<4096, 256, 0, stream>>>(qb, kb, vb, attn_b);
    gemm_bt<<<1024, 256, 0, stream>>>(
        attn_b, WtO + (size_t)l * EMB * EMB, EMB, /*mode=*/1,
        bo + l * EMB, nullptr, nullptr, x, nullptr, nullptr, x, EMB);
  }
  out_proj<<<8192, 256, 0, stream>>>(x, Wout, bout, outp);
}

// Round 10
// 783.246 us; speedup vs baseline: 1.2753x; 1.0478x over previous
//
#include <hip/hip_runtime.h>

typedef unsigned short u16;
typedef unsigned int u32;
using short8  = __attribute__((ext_vector_type(8))) short;
using floatx4 = __attribute__((ext_vector_type(4))) float;

#define NB 32
#define SEQ 1024
#define EMB 512
#define NH 8
#define HD 64
#define NLAYER 2
#define M_ROWS (NB * SEQ)   // 32768

__device__ __forceinline__ float bf2f(u16 u) {
  union { u32 i; float f; } v; v.i = ((u32)u) << 16; return v.f;
}
__device__ __forceinline__ u16 f2bf(float f) {
  union { float f; u32 i; } v; v.f = f;
  u32 r = v.i + 0x7fffu + ((v.i >> 16) & 1u);
  return (u16)(r >> 16);
}

// async global->LDS, 16B per lane. LDS dest = wave-uniform base + lane*16.
typedef __attribute__((address_space(3))) unsigned int lds_u32_t;
typedef __attribute__((address_space(1))) const unsigned int gbl_u32_t;
__device__ __forceinline__ void gload16(void* lds, const void* g) {
  gbl_u32_t* gp = (gbl_u32_t*)(unsigned long long)g;
  lds_u32_t* lp = (lds_u32_t*)(unsigned int)(unsigned long long)lds;
  __builtin_amdgcn_global_load_lds(gp, lp, 16, 0, 0);
}

// ---------------- weight pre-transpose + fp32->bf16: W[K,N] -> Bt[N,K] ------
__global__ void prep_weights(const float* __restrict__ Wq, const float* __restrict__ Wk,
                             const float* __restrict__ Wv, const float* __restrict__ Wo,
                             u16* __restrict__ WtQKV, u16* __restrict__ WtO) {
  int idx = blockIdx.x * 256 + threadIdx.x;
  const int QKV_TOT = NLAYER * 3 * EMB * EMB;
  if (idx < QKV_TOT) {
    int l = idx / (3 * EMB * EMB);
    int rem = idx % (3 * EMB * EMB);
    int n = rem / EMB, kk = rem % EMB;
    int w = n >> 9, e = n & 511;
    const float* src = (w == 0) ? Wq : (w == 1) ? Wk : Wv;
    WtQKV[idx] = f2bf(src[((size_t)l * EMB + kk) * EMB + e]);
  } else {
    int j = idx - QKV_TOT;
    int l = j / (EMB * EMB);
    int rem = j % (EMB * EMB);
    int n = rem / EMB, kk = rem % EMB;
    WtO[j] = f2bf(Wo[((size_t)l * EMB + kk) * EMB + n]);
  }
}

// ---------------- embedding + positional encoding (fp32 in, bf16 out) -------
__global__ void embed_pe(const int* __restrict__ inp, const float* __restrict__ table,
                         u16* __restrict__ x) {
  int row = blockIdx.x;
  int tok = inp[row];
  int s = row & (SEQ - 1);
  const float negln = -9.210340371976184f / (float)EMB;
  for (int e = threadIdx.x; e < EMB; e += blockDim.x) {
    float val = table[(size_t)tok * EMB + e];
    int i = e >> 1;
    float dt = __expf((float)(2 * i) * negln);
    float ang = (float)s * dt;
    float pe = (e & 1) ? __cosf(ang) : __sinf(ang);
    x[(size_t)row * EMB + e] = f2bf(val + pe);
  }
}

// ---------------- GEMM: C[M,N] = A[M,K] @ Bt[N,K]^T + bias ------------------
// XCD-aware 1-D grid. Double-buffered K-loop (vmcnt(4) + raw s_barrier),
// lgkmcnt(0) before the trailing barrier closes the read-in-flight race.
// Swizzle: chunk c of row R at slot c^((R>>1)&3) -> 2-way (free).
// mode 0: N=1536 (NT=12). Q (*0.125 folded), K -> [B,H,S,D]; V (bn0>=1024):
//         operand-swapped MFMA -> [B,H,D,S] stores sid-contiguous.
// mode 1: N=512 (NT=4),  x = x + relu(C + bias)  (in place, out0 == resid)
#define BK 32

__global__ __launch_bounds__(256) void gemm_bt(
    const u16* __restrict__ A, const u16* __restrict__ Bt, int K, int mode,
    const float* bias0, const float* bias1, const float* bias2,
    u16* out0, u16* out1, u16* out2, const u16* resid, int Nstride) {
  __shared__ u16 sA[2][128][BK];
  __shared__ u16 sB[2][128][BK];
  int tid = threadIdx.x;
  int wave = tid >> 6, lane = tid & 63;
  int quad = lane >> 4, l16 = lane & 15;
  int wm = wave >> 1, wn = wave & 1;

  int NT = (mode == 0) ? 12 : 4;          // N-tiles per M-tile
  int blk = blockIdx.x;
  int xcd = blk & 7, slot = blk >> 3;
  int mtl = slot / NT, ntl = slot % NT;   // 32 M-tiles per XCD, N-tiles inner
  int bm0 = (xcd * 32 + mtl) * 128;
  int bn0 = ntl * 128;
  bool vswap = (mode == 0) && (bn0 >= 1024);

  floatx4 acc[4][4];
#pragma unroll
  for (int i = 0; i < 4; ++i)
#pragma unroll
    for (int j = 0; j < 4; ++j) acc[i][j] = (floatx4){0.f, 0.f, 0.f, 0.f};

  int rb = wave * 32;                         // wave stages rows rb..rb+31
  int lrow = lane >> 2;                       // 0..15
  int gcg = ((lane & 3) ^ ((lane >> 3) & 3)) * 8;  // fetch chunk for slot lane&3
  int rsl = (quad ^ ((l16 >> 1) & 3)) * 8;    // read slot holding chunk `quad`

  const u16* Arow0 = &A[(size_t)(bm0 + rb + lrow) * K + gcg];
  const u16* Arow1 = &A[(size_t)(bm0 + rb + 16 + lrow) * K + gcg];
  const u16* Brow0 = &Bt[(size_t)(bn0 + rb + lrow) * K + gcg];
  const u16* Brow1 = &Bt[(size_t)(bn0 + rb + 16 + lrow) * K + gcg];

  // prologue: stage k-tile 0 into buffer 0 (4 loads per wave)
  gload16(&sA[0][rb][0],      Arow0);
  gload16(&sA[0][rb + 16][0], Arow1);
  gload16(&sB[0][rb][0],      Brow0);
  gload16(&sB[0][rb + 16][0], Brow1);

  const int niter = K / BK;
  int ibuf = 0;
  for (int it = 0; it < niter; ++it) {
    if (it + 1 < niter) {
      int k1 = (it + 1) * BK;
      int nb = ibuf ^ 1;
      gload16(&sA[nb][rb][0],      Arow0 + k1);
      gload16(&sA[nb][rb + 16][0], Arow1 + k1);
      gload16(&sB[nb][rb][0],      Brow0 + k1);
      gload16(&sB[nb][rb + 16][0], Brow1 + k1);
      asm volatile("s_waitcnt vmcnt(4)" ::: "memory");  // current buf's 4 done
    } else {
      asm volatile("s_waitcnt vmcnt(0)" ::: "memory");
    }
    asm volatile("s_barrier" ::: "memory");             // buf ready for all

    short8 af[4], bfr[4];
#pragma unroll
    for (int mi = 0; mi < 4; ++mi)
      af[mi] = *(const short8*)&sA[ibuf][wm * 64 + mi * 16 + l16][rsl];
#pragma unroll
    for (int ni = 0; ni < 4; ++ni)
      bfr[ni] = *(const short8*)&sB[ibuf][wn * 64 + ni * 16 + l16][rsl];
    if (!vswap) {
#pragma unroll
      for (int mi = 0; mi < 4; ++mi)
#pragma unroll
        for (int ni = 0; ni < 4; ++ni)
          acc[mi][ni] = __builtin_amdgcn_mfma_f32_16x16x32_bf16(af[mi], bfr[ni], acc[mi][ni], 0, 0, 0);
    } else {
#pragma unroll
      for (int mi = 0; mi < 4; ++mi)
#pragma unroll
        for (int ni = 0; ni < 4; ++ni)
          acc[mi][ni] = __builtin_amdgcn_mfma_f32_16x16x32_bf16(bfr[ni], af[mi], acc[mi][ni], 0, 0, 0);
    }
    asm volatile("s_waitcnt lgkmcnt(0)" ::: "memory");  // all ds_reads complete
    asm volatile("s_barrier" ::: "memory");             // before buf overwrite
    ibuf ^= 1;
  }

#pragma unroll
  for (int mi = 0; mi < 4; ++mi) {
#pragma unroll
    for (int ni = 0; ni < 4; ++ni) {
#pragma unroll
      for (int r = 0; r < 4; ++r) {
        float v = acc[mi][ni][r];
        if (vswap) {
          // D rows = weight rows (d), D cols = x rows (sid)
          int n = bn0 + wn * 64 + ni * 16 + quad * 4 + r;
          int m = bm0 + wm * 64 + mi * 16 + l16;
          int e = n & 511, h = (n >> 6) & 7, d = n & 63;
          int b = m >> 10, sid = m & 1023;
          v += bias2[e];
          out2[((size_t)(b * NH + h) * HD + d) * SEQ + sid] = f2bf(v);
        } else {
          int m = bm0 + wm * 64 + mi * 16 + quad * 4 + r;
          int n = bn0 + wn * 64 + ni * 16 + l16;
          if (mode == 0) {
            int w = n >> 9, e = n & 511;
            int h = e >> 6, d = e & 63;
            const float* bptr = (w == 0) ? bias0 : bias1;
            v += bptr[e];
            if (w == 0) v *= 0.125f;      // fold 1/sqrt(D) into Q
            u16* optr = (w == 0) ? out0 : out1;
            int b = m >> 10, sid = m & 1023;
            optr[((size_t)(b * NH + h) * SEQ + sid) * HD + d] = f2bf(v);
          } else {
            v += bias0[n];
            v = fmaxf(v, 0.f);
            v += bf2f(resid[(size_t)m * Nstride + n]);
            out0[(size_t)m * Nstride + n] = f2bf(v);
          }
        }
      }
    }
  }
}

// ---------------- flash attention, causal ----------------------------------
// XCD-aware mapping; round-8 __syncthreads staging (known-good) + round-9
// algorithmic wins: ones-MFMA row sums (no sum shuffles), hoisted Q frags,
// Q pre-scaled by 1/8 in the QKV epilogue.
__device__ __forceinline__ void stage_tile64(u16 (*dst)[64], const u16* g, int gstride,
                                             int wave, int lane) {
  int r = lane >> 3;
  int gcg = ((lane & 7) ^ r) * 8;
#pragma unroll
  for (int c = 0; c < 2; ++c) {
    int row0 = (wave * 2 + c) * 8;
    gload16(&dst[row0][0], &g[(size_t)(row0 + r) * gstride + gcg]);
  }
}
#define RD8(T, row, cg) (*(const short8*)&T[row][(((cg) ^ ((row) & 7)) * 8)])

__global__ __launch_bounds__(256) void attn_kernel(
    const u16* __restrict__ q, const u16* __restrict__ k, const u16* __restrict__ vt,
    u16* __restrict__ o) {
  int blk = blockIdx.x;          // 0..4095
  int xcd = blk & 7, slot = blk >> 3;
  int bh = xcd * 32 + (slot >> 4);   // 32 bh's per XCD, 16 blocks each, consecutive
  int qt = slot & 15;
  int b = bh >> 3, h = bh & 7;
  int q0 = qt * 64;
  __shared__ u16 sQ[64][64], sK[64][64], sV[64][64];
  __shared__ u16 sP[64][68];
  int tid = threadIdx.x, wave = tid >> 6, lane = tid & 63;
  int quad = lane >> 4, l16 = lane & 15;

  stage_tile64(sQ, &q[((size_t)bh * SEQ + q0) * HD], HD, wave, lane);

  short8 ones;
#pragma unroll
  for (int j = 0; j < 8; ++j) ones[j] = (short)0x3F80;   // bf16 1.0

  floatx4 acco[4], accsum;
#pragma unroll
  for (int i = 0; i < 4; ++i) acco[i] = (floatx4){0.f, 0.f, 0.f, 0.f};
  accsum = (floatx4){0.f, 0.f, 0.f, 0.f};
  float mrow[4];
#pragma unroll
  for (int r = 0; r < 4; ++r) mrow[r] = -INFINITY;
  short8 aq0 = {}, aq1 = {};

  for (int kt = 0; kt <= qt; ++kt) {
    int k0 = kt * 64;
    __syncthreads();   // previous iter's sK/sV reads done (and sQ at kt=0)
    stage_tile64(sK, &k[((size_t)bh * SEQ + k0) * HD], HD, wave, lane);
    stage_tile64(sV, &vt[(size_t)bh * HD * SEQ + k0], SEQ, wave, lane);
    __syncthreads();   // drains vmcnt -> staged data visible

    if (kt == 0) {   // hoist Q fragments (sQ valid; wave-private rows)
      int ra = wave * 16 + l16;
      aq0 = RD8(sQ, ra, quad);
      aq1 = RD8(sQ, ra, 4 + quad);
    }

    // S = Q @ K^T (Q pre-scaled by 1/8); wave: 16 q-rows x 64 keys
    floatx4 accs[4];
#pragma unroll
    for (int i = 0; i < 4; ++i) accs[i] = (floatx4){0.f, 0.f, 0.f, 0.f};
#pragma unroll
    for (int nt = 0; nt < 4; ++nt) {
      int rbk = nt * 16 + l16;
      accs[nt] = __builtin_amdgcn_mfma_f32_16x16x32_bf16(aq0, RD8(sK, rbk, quad), accs[nt], 0, 0, 0);
      accs[nt] = __builtin_amdgcn_mfma_f32_16x16x32_bf16(aq1, RD8(sK, rbk, 4 + quad), accs[nt], 0, 0, 0);
    }

    // online softmax; only the diagonal tile needs masking; max via 4 shfl
    bool diag = (kt == qt);
    int qg_base = q0 + wave * 16 + quad * 4;
    float pvv[4][4];
#pragma unroll
    for (int r = 0; r < 4; ++r) {
      float mx = -INFINITY;
#pragma unroll
      for (int nt = 0; nt < 4; ++nt) {
        float s = accs[nt][r];
        if (diag) {
          int kg = k0 + nt * 16 + l16;
          if (kg > qg_base + r) s = -INFINITY;
        }
        pvv[nt][r] = s;
        mx = fmaxf(mx, s);
      }
#pragma unroll
      for (int sh = 1; sh < 16; sh <<= 1) mx = fmaxf(mx, __shfl_xor(mx, sh, 64));
      float mn = fmaxf(mrow[r], mx);
      float alpha = __expf(mrow[r] - mn);
      mrow[r] = mn;
#pragma unroll
      for (int nt = 0; nt < 4; ++nt) pvv[nt][r] = __expf(pvv[nt][r] - mn);
      accsum[r] *= alpha;
#pragma unroll
      for (int dt = 0; dt < 4; ++dt) acco[dt][r] *= alpha;
    }

    // P (C-layout) -> LDS -> A-layout. Wave-private rows: lgkmcnt drain only.
#pragma unroll
    for (int nt = 0; nt < 4; ++nt)
#pragma unroll
      for (int r = 0; r < 4; ++r)
        sP[wave * 16 + quad * 4 + r][nt * 16 + l16] =
            (u16)(__float_as_uint(pvv[nt][r]) >> 16);   // truncate: P in [0,1]
    asm volatile("s_waitcnt lgkmcnt(0)" ::: "memory");

#pragma unroll
    for (int cst = 0; cst < 2; ++cst) {
      short8 ap = *(const short8*)&sP[wave * 16 + l16][cst * 32 + quad * 8];
#pragma unroll
      for (int dt = 0; dt < 4; ++dt) {
        int rv = dt * 16 + l16;
        acco[dt] = __builtin_amdgcn_mfma_f32_16x16x32_bf16(ap, RD8(sV, rv, cst * 4 + quad), acco[dt], 0, 0, 0);
      }
      accsum = __builtin_amdgcn_mfma_f32_16x16x32_bf16(ap, ones, accsum, 0, 0, 0);  // row sums
    }
  }

  // normalize + write [B,S,E]
#pragma unroll
  for (int dt = 0; dt < 4; ++dt)
#pragma unroll
    for (int r = 0; r < 4; ++r) {
      float ov = acco[dt][r] / accsum[r];
      int srow = q0 + wave * 16 + quad * 4 + r;
      int col = h * HD + dt * 16 + l16;
      o[((size_t)b * SEQ + srow) * EMB + col] = f2bf(ov);
    }
}

// ---------------- output head: out[m] = x[m,:] . W_out + b_out (fp32 out) ---
__global__ __launch_bounds__(256) void out_proj(const u16* __restrict__ x,
                                                const float* __restrict__ wout,
                                                const float* __restrict__ bout,
                                                float* __restrict__ out) {
  int wave = threadIdx.x >> 6, lane = threadIdx.x & 63;
  int m = blockIdx.x * 4 + wave;
  union { uint4 vv; u16 s[8]; } xv;
  xv.vv = *(const uint4*)&x[(size_t)m * EMB + lane * 8];
  float4 w0 = *(const float4*)&wout[lane * 8];
  float4 w1 = *(const float4*)&wout[lane * 8 + 4];
  float wv[8] = {w0.x, w0.y, w0.z, w0.w, w1.x, w1.y, w1.z, w1.w};
  float s = 0.f;
#pragma unroll
  for (int j = 0; j < 8; ++j) s += bf2f(xv.s[j]) * wv[j];
#pragma unroll
  for (int sh = 1; sh < 64; sh <<= 1) s += __shfl_xor(s, sh, 64);
  if (lane == 0) out[m] = s + bout[0];
}

extern "C" void kernel_launch(void* const* d_in, const int* in_sizes, int n_in,
                              void* d_out, int out_size, void* d_ws, size_t ws_size,
                              hipStream_t stream) {
  const int*   inp   = (const int*)d_in[0];
  const float* table = (const float*)d_in[1];
  const float* Wq    = (const float*)d_in[2];
  const float* bq    = (const float*)d_in[3];
  const float* Wk    = (const float*)d_in[4];
  const float* bk    = (const float*)d_in[5];
  const float* Wv    = (const float*)d_in[6];
  const float* bv    = (const float*)d_in[7];
  const float* Wo    = (const float*)d_in[8];
  const float* bo    = (const float*)d_in[9];
  const float* Wout  = (const float*)d_in[10];
  const float* bout  = (const float*)d_in[11];
  float* outp = (float*)d_out;

  char* ws = (char*)d_ws;
  const size_t SZ = (size_t)M_ROWS * EMB * 2;  // 32 MB
  u16* x      = (u16*)(ws);
  u16* qb     = (u16*)(ws + SZ);
  u16* kb     = (u16*)(ws + 2 * SZ);
  u16* vb     = (u16*)(ws + 3 * SZ);   // [B,H,D,S]
  u16* attn_b = (u16*)(ws + 4 * SZ);
  u16* WtQKV  = (u16*)(ws + 5 * SZ);
  u16* WtO    = (u16*)(ws + 5 * SZ + (size_t)NLAYER * 3 * EMB * EMB * 2);

  prep_weights<<<8192, 256, 0, stream>>>(Wq, Wk, Wv, Wo, WtQKV, WtO);
  embed_pe<<<M_ROWS, 256, 0, stream>>>(inp, table, x);

  for (int l = 0; l < NLAYER; ++l) {
    gemm_bt<<<3072, 256, 0, stream>>>(
        x, WtQKV + (size_t)l * 3 * EMB * EMB, EMB, /*mode=*/0,
        bq + l * EMB, bk + l * EMB, bv + l * EMB, qb, kb, vb, nullptr, 0);
    attn_kernel<<<4096, 256, 0, stream>>>(qb, kb, vb, attn_b);
    gemm_bt<<<1024, 256, 0, stream>>>(
        attn_b, WtO + (size_t)l * EMB * EMB, EMB, /*mode=*/1,
        bo + l * EMB, nullptr, nullptr, x, nullptr, nullptr, x, EMB);
  }
  out_proj<<<8192, 256, 0, stream>>>(x, Wout, bout, outp);
}

// Round 11
// 663.405 us; speedup vs baseline: 1.5056x; 1.1806x over previous
//
#include <hip/hip_runtime.h>

typedef unsigned short u16;
typedef unsigned int u32;
using short8  = __attribute__((ext_vector_type(8))) short;
using floatx4 = __attribute__((ext_vector_type(4))) float;

#define NB 32
#define SEQ 1024
#define EMB 512
#define NH 8
#define HD 64
#define NLAYER 2
#define M_ROWS (NB * SEQ)   // 32768

__device__ __forceinline__ float bf2f(u16 u) {
  union { u32 i; float f; } v; v.i = ((u32)u) << 16; return v.f;
}
__device__ __forceinline__ u16 f2bf(float f) {
  union { float f; u32 i; } v; v.f = f;
  u32 r = v.i + 0x7fffu + ((v.i >> 16) & 1u);
  return (u16)(r >> 16);
}

// async global->LDS, 16B per lane. LDS dest = wave-uniform base + lane*16.
typedef __attribute__((address_space(3))) unsigned int lds_u32_t;
typedef __attribute__((address_space(1))) const unsigned int gbl_u32_t;
__device__ __forceinline__ void gload16(void* lds, const void* g) {
  gbl_u32_t* gp = (gbl_u32_t*)(unsigned long long)g;
  lds_u32_t* lp = (lds_u32_t*)(unsigned int)(unsigned long long)lds;
  __builtin_amdgcn_global_load_lds(gp, lp, 16, 0, 0);
}

// ---------------- weight pre-transpose + fp32->bf16: W[K,N] -> Bt[N,K] ------
__global__ void prep_weights(const float* __restrict__ Wq, const float* __restrict__ Wk,
                             const float* __restrict__ Wv, const float* __restrict__ Wo,
                             u16* __restrict__ WtQKV, u16* __restrict__ WtO) {
  int idx = blockIdx.x * 256 + threadIdx.x;
  const int QKV_TOT = NLAYER * 3 * EMB * EMB;
  if (idx < QKV_TOT) {
    int l = idx / (3 * EMB * EMB);
    int rem = idx % (3 * EMB * EMB);
    int n = rem / EMB, kk = rem % EMB;
    int w = n >> 9, e = n & 511;
    const float* src = (w == 0) ? Wq : (w == 1) ? Wk : Wv;
    WtQKV[idx] = f2bf(src[((size_t)l * EMB + kk) * EMB + e]);
  } else {
    int j = idx - QKV_TOT;
    int l = j / (EMB * EMB);
    int rem = j % (EMB * EMB);
    int n = rem / EMB, kk = rem % EMB;
    WtO[j] = f2bf(Wo[((size_t)l * EMB + kk) * EMB + n]);
  }
}

// ---------------- embedding + positional encoding (fp32 in, bf16 out) -------
__global__ void embed_pe(const int* __restrict__ inp, const float* __restrict__ table,
                         u16* __restrict__ x) {
  int row = blockIdx.x;
  int tok = inp[row];
  int s = row & (SEQ - 1);
  const float negln = -9.210340371976184f / (float)EMB;
  for (int e = threadIdx.x; e < EMB; e += blockDim.x) {
    float val = table[(size_t)tok * EMB + e];
    int i = e >> 1;
    float dt = __expf((float)(2 * i) * negln);
    float ang = (float)s * dt;
    float pe = (e & 1) ? __cosf(ang) : __sinf(ang);
    x[(size_t)row * EMB + e] = f2bf(val + pe);
  }
}

// ---------------- GEMM: C[M,N] = A[M,K] @ Bt[N,K]^T + bias ------------------
// XCD-aware 1-D grid. Double-buffered K-loop (vmcnt(4) + raw s_barrier),
// lgkmcnt(0) before the trailing barrier closes the read-in-flight race.
// Epilogue: per-wave LDS repack (stride 68: b16 writes 2-way free, b32 reads
// conflict-free) -> coalesced 128B dword-row stores.
// mode 0: N=1536 (NT=12). Q (*0.125 folded), K -> [B,H,S,D]; V (bn0>=1024):
//         operand-swapped MFMA -> [B,H,D,S] stores sid-contiguous.
// mode 1: N=512 (NT=4),  x = x + relu(C + bias)  (in place, out0 == resid)
#define BK 32

__global__ __launch_bounds__(256) void gemm_bt(
    const u16* __restrict__ A, const u16* __restrict__ Bt, int K, int mode,
    const float* bias0, const float* bias1, const float* bias2,
    u16* out0, u16* out1, u16* out2, const u16* resid, int Nstride) {
  __shared__ u16 sA[2][128][BK];
  __shared__ u16 sB[2][128][BK];
  int tid = threadIdx.x;
  int wave = tid >> 6, lane = tid & 63;
  int quad = lane >> 4, l16 = lane & 15;
  int wm = wave >> 1, wn = wave & 1;

  int NT = (mode == 0) ? 12 : 4;          // N-tiles per M-tile
  int blk = blockIdx.x;
  int xcd = blk & 7, slot = blk >> 3;
  int mtl = slot / NT, ntl = slot % NT;   // 32 M-tiles per XCD, N-tiles inner
  int bm0 = (xcd * 32 + mtl) * 128;
  int bn0 = ntl * 128;
  bool vswap = (mode == 0) && (bn0 >= 1024);

  floatx4 acc[4][4];
#pragma unroll
  for (int i = 0; i < 4; ++i)
#pragma unroll
    for (int j = 0; j < 4; ++j) acc[i][j] = (floatx4){0.f, 0.f, 0.f, 0.f};

  int rb = wave * 32;                         // wave stages rows rb..rb+31
  int lrow = lane >> 2;                       // 0..15
  int gcg = ((lane & 3) ^ ((lane >> 3) & 3)) * 8;  // fetch chunk for slot lane&3
  int rsl = (quad ^ ((l16 >> 1) & 3)) * 8;    // read slot holding chunk `quad`

  const u16* Arow0 = &A[(size_t)(bm0 + rb + lrow) * K + gcg];
  const u16* Arow1 = &A[(size_t)(bm0 + rb + 16 + lrow) * K + gcg];
  const u16* Brow0 = &Bt[(size_t)(bn0 + rb + lrow) * K + gcg];
  const u16* Brow1 = &Bt[(size_t)(bn0 + rb + 16 + lrow) * K + gcg];

  // prologue: stage k-tile 0 into buffer 0 (4 loads per wave)
  gload16(&sA[0][rb][0],      Arow0);
  gload16(&sA[0][rb + 16][0], Arow1);
  gload16(&sB[0][rb][0],      Brow0);
  gload16(&sB[0][rb + 16][0], Brow1);

  const int niter = K / BK;
  int ibuf = 0;
  for (int it = 0; it < niter; ++it) {
    if (it + 1 < niter) {
      int k1 = (it + 1) * BK;
      int nb = ibuf ^ 1;
      gload16(&sA[nb][rb][0],      Arow0 + k1);
      gload16(&sA[nb][rb + 16][0], Arow1 + k1);
      gload16(&sB[nb][rb][0],      Brow0 + k1);
      gload16(&sB[nb][rb + 16][0], Brow1 + k1);
      asm volatile("s_waitcnt vmcnt(4)" ::: "memory");  // current buf's 4 done
    } else {
      asm volatile("s_waitcnt vmcnt(0)" ::: "memory");
    }
    asm volatile("s_barrier" ::: "memory");             // buf ready for all

    short8 af[4], bfr[4];
#pragma unroll
    for (int mi = 0; mi < 4; ++mi)
      af[mi] = *(const short8*)&sA[ibuf][wm * 64 + mi * 16 + l16][rsl];
#pragma unroll
    for (int ni = 0; ni < 4; ++ni)
      bfr[ni] = *(const short8*)&sB[ibuf][wn * 64 + ni * 16 + l16][rsl];
    if (!vswap) {
#pragma unroll
      for (int mi = 0; mi < 4; ++mi)
#pragma unroll
        for (int ni = 0; ni < 4; ++ni)
          acc[mi][ni] = __builtin_amdgcn_mfma_f32_16x16x32_bf16(af[mi], bfr[ni], acc[mi][ni], 0, 0, 0);
    } else {
#pragma unroll
      for (int mi = 0; mi < 4; ++mi)
#pragma unroll
        for (int ni = 0; ni < 4; ++ni)
          acc[mi][ni] = __builtin_amdgcn_mfma_f32_16x16x32_bf16(bfr[ni], af[mi], acc[mi][ni], 0, 0, 0);
    }
    asm volatile("s_waitcnt lgkmcnt(0)" ::: "memory");  // all ds_reads complete
    asm volatile("s_barrier" ::: "memory");             // before buf overwrite
    ibuf ^= 1;
  }

  // ---- epilogue: wave-private LDS repack -> coalesced dword-row stores ----
  // scr: 16 rows x 64 cols (stride 68), one subtile at a time. After the
  // K-loop's trailing barrier, sA is free; regions are wave-private.
  u16* scr = ((u16*)sA) + wave * (16 * 68);
  int erow = lane >> 5;            // 0..1: row within a read pass
  int dcol = lane & 31;            // dword column (2 bf16 per dword)

  if (!vswap) {
    int w = bn0 >> 9;                                   // 0=Q, 1=K (mode 0)
    const float* bp = (mode == 1) ? bias0 : ((w == 0) ? bias0 : bias1);
    float sc = (mode == 0 && w == 0) ? 0.125f : 1.0f;   // fold 1/sqrt(D) into Q
    float bv[4];
#pragma unroll
    for (int ni = 0; ni < 4; ++ni)
      bv[ni] = bp[(bn0 + wn * 64 + ni * 16 + l16) & 511];

#pragma unroll
    for (int mi = 0; mi < 4; ++mi) {
#pragma unroll
      for (int ni = 0; ni < 4; ++ni)
#pragma unroll
        for (int r = 0; r < 4; ++r) {
          float t = (acc[mi][ni][r] + bv[ni]) * sc;
          if (mode == 1) t = fmaxf(t, 0.f);
          scr[(quad * 4 + r) * 68 + ni * 16 + l16] = f2bf(t);
        }
      asm volatile("s_waitcnt lgkmcnt(0)" ::: "memory");  // wave-private: no barrier

      int m0 = bm0 + wm * 64 + mi * 16;
      int colg = bn0 + wn * 64 + dcol * 2;
#pragma unroll
      for (int p = 0; p < 8; ++p) {
        int row = p * 2 + erow;
        u32 d2 = *(const u32*)&scr[row * 68 + dcol * 2];
        int m = m0 + row;
        if (mode == 0) {
          int e = colg & 511, h = e >> 6, d = e & 63;
          int b = m >> 10, sid = m & 1023;
          u16* optr = (w == 0) ? out0 : out1;
          *(u32*)&optr[((size_t)(b * NH + h) * SEQ + sid) * HD + d] = d2;
        } else {
          size_t off = (size_t)m * Nstride + colg;
          u32 rs = *(const u32*)&resid[off];
          float lo = bf2f((u16)d2) + bf2f((u16)rs);
          float hi = bf2f((u16)(d2 >> 16)) + bf2f((u16)(rs >> 16));
          *(u32*)&out0[off] = ((u32)f2bf(hi) << 16) | f2bf(lo);
        }
      }
      asm volatile("s_waitcnt lgkmcnt(0)" ::: "memory");  // reads done before rewrite
    }
  } else {
    // V section: D rows = weight rows (d), D cols = x rows (sid)
    float bvv[4][4];
#pragma unroll
    for (int ni = 0; ni < 4; ++ni)
#pragma unroll
      for (int r = 0; r < 4; ++r)
        bvv[ni][r] = bias2[(bn0 + wn * 64 + ni * 16 + quad * 4 + r) & 511];

    int b = (bm0 + wm * 64) >> 10;
    int sid0 = (bm0 + wm * 64) & 1023;
    int n0 = bn0 + wn * 64;
    int h = (n0 >> 6) & 7;
#pragma unroll
    for (int ni = 0; ni < 4; ++ni) {
#pragma unroll
      for (int mi = 0; mi < 4; ++mi)
#pragma unroll
        for (int r = 0; r < 4; ++r)
          scr[(quad * 4 + r) * 68 + mi * 16 + l16] = f2bf(acc[mi][ni][r] + bvv[ni][r]);
      asm volatile("s_waitcnt lgkmcnt(0)" ::: "memory");

      int d0 = (n0 & 63) + ni * 16;
#pragma unroll
      for (int p = 0; p < 8; ++p) {
        int row = p * 2 + erow;
        u32 d2 = *(const u32*)&scr[row * 68 + dcol * 2];
        *(u32*)&out2[((size_t)(b * NH + h) * HD + d0 + row) * SEQ + sid0 + dcol * 2] = d2;
      }
      asm volatile("s_waitcnt lgkmcnt(0)" ::: "memory");
    }
  }
}

// ---------------- flash attention, causal ----------------------------------
// XCD-aware mapping; __syncthreads staging (known-good) + ones-MFMA row sums,
// hoisted Q frags, Q pre-scaled by 1/8 in the QKV epilogue.
__device__ __forceinline__ void stage_tile64(u16 (*dst)[64], const u16* g, int gstride,
                                             int wave, int lane) {
  int r = lane >> 3;
  int gcg = ((lane & 7) ^ r) * 8;
#pragma unroll
  for (int c = 0; c < 2; ++c) {
    int row0 = (wave * 2 + c) * 8;
    gload16(&dst[row0][0], &g[(size_t)(row0 + r) * gstride + gcg]);
  }
}
#define RD8(T, row, cg) (*(const short8*)&T[row][(((cg) ^ ((row) & 7)) * 8)])

__global__ __launch_bounds__(256) void attn_kernel(
    const u16* __restrict__ q, const u16* __restrict__ k, const u16* __restrict__ vt,
    u16* __restrict__ o) {
  int blk = blockIdx.x;          // 0..4095
  int xcd = blk & 7, slot = blk >> 3;
  int bh = xcd * 32 + (slot >> 4);   // 32 bh's per XCD, 16 blocks each, consecutive
  int qt = slot & 15;
  int b = bh >> 3, h = bh & 7;
  int q0 = qt * 64;
  __shared__ u16 sQ[64][64], sK[64][64], sV[64][64];
  __shared__ u16 sP[64][68];
  int tid = threadIdx.x, wave = tid >> 6, lane = tid & 63;
  int quad = lane >> 4, l16 = lane & 15;

  stage_tile64(sQ, &q[((size_t)bh * SEQ + q0) * HD], HD, wave, lane);

  short8 ones;
#pragma unroll
  for (int j = 0; j < 8; ++j) ones[j] = (short)0x3F80;   // bf16 1.0

  floatx4 acco[4], accsum;
#pragma unroll
  for (int i = 0; i < 4; ++i) acco[i] = (floatx4){0.f, 0.f, 0.f, 0.f};
  accsum = (floatx4){0.f, 0.f, 0.f, 0.f};
  float mrow[4];
#pragma unroll
  for (int r = 0; r < 4; ++r) mrow[r] = -INFINITY;
  short8 aq0 = {}, aq1 = {};

  for (int kt = 0; kt <= qt; ++kt) {
    int k0 = kt * 64;
    __syncthreads();   // previous iter's sK/sV reads done (and sQ at kt=0)
    stage_tile64(sK, &k[((size_t)bh * SEQ + k0) * HD], HD, wave, lane);
    stage_tile64(sV, &vt[(size_t)bh * HD * SEQ + k0], SEQ, wave, lane);
    __syncthreads();   // drains vmcnt -> staged data visible

    if (kt == 0) {   // hoist Q fragments (sQ valid; wave-private rows)
      int ra = wave * 16 + l16;
      aq0 = RD8(sQ, ra, quad);
      aq1 = RD8(sQ, ra, 4 + quad);
    }

    // S = Q @ K^T (Q pre-scaled by 1/8); wave: 16 q-rows x 64 keys
    floatx4 accs[4];
#pragma unroll
    for (int i = 0; i < 4; ++i) accs[i] = (floatx4){0.f, 0.f, 0.f, 0.f};
#pragma unroll
    for (int nt = 0; nt < 4; ++nt) {
      int rbk = nt * 16 + l16;
      accs[nt] = __builtin_amdgcn_mfma_f32_16x16x32_bf16(aq0, RD8(sK, rbk, quad), accs[nt], 0, 0, 0);
      accs[nt] = __builtin_amdgcn_mfma_f32_16x16x32_bf16(aq1, RD8(sK, rbk, 4 + quad), accs[nt], 0, 0, 0);
    }

    // online softmax; only the diagonal tile needs masking; max via 4 shfl
    bool diag = (kt == qt);
    int qg_base = q0 + wave * 16 + quad * 4;
    float pvv[4][4];
#pragma unroll
    for (int r = 0; r < 4; ++r) {
      float mx = -INFINITY;
#pragma unroll
      for (int nt = 0; nt < 4; ++nt) {
        float s = accs[nt][r];
        if (diag) {
          int kg = k0 + nt * 16 + l16;
          if (kg > qg_base + r) s = -INFINITY;
        }
        pvv[nt][r] = s;
        mx = fmaxf(mx, s);
      }
#pragma unroll
      for (int sh = 1; sh < 16; sh <<= 1) mx = fmaxf(mx, __shfl_xor(mx, sh, 64));
      float mn = fmaxf(mrow[r], mx);
      float alpha = __expf(mrow[r] - mn);
      mrow[r] = mn;
#pragma unroll
      for (int nt = 0; nt < 4; ++nt) pvv[nt][r] = __expf(pvv[nt][r] - mn);
      accsum[r] *= alpha;
#pragma unroll
      for (int dt = 0; dt < 4; ++dt) acco[dt][r] *= alpha;
    }

    // P (C-layout) -> LDS -> A-layout. Wave-private rows: lgkmcnt drain only.
#pragma unroll
    for (int nt = 0; nt < 4; ++nt)
#pragma unroll
      for (int r = 0; r < 4; ++r)
        sP[wave * 16 + quad * 4 + r][nt * 16 + l16] =
            (u16)(__float_as_uint(pvv[nt][r]) >> 16);   // truncate: P in [0,1]
    asm volatile("s_waitcnt lgkmcnt(0)" ::: "memory");

#pragma unroll
    for (int cst = 0; cst < 2; ++cst) {
      short8 ap = *(const short8*)&sP[wave * 16 + l16][cst * 32 + quad * 8];
#pragma unroll
      for (int dt = 0; dt < 4; ++dt) {
        int rv = dt * 16 + l16;
        acco[dt] = __builtin_amdgcn_mfma_f32_16x16x32_bf16(ap, RD8(sV, rv, cst * 4 + quad), acco[dt], 0, 0, 0);
      }
      accsum = __builtin_amdgcn_mfma_f32_16x16x32_bf16(ap, ones, accsum, 0, 0, 0);  // row sums
    }
  }

  // normalize + write [B,S,E]
#pragma unroll
  for (int dt = 0; dt < 4; ++dt)
#pragma unroll
    for (int r = 0; r < 4; ++r) {
      float ov = acco[dt][r] / accsum[r];
      int srow = q0 + wave * 16 + quad * 4 + r;
      int col = h * HD + dt * 16 + l16;
      o[((size_t)b * SEQ + srow) * EMB + col] = f2bf(ov);
    }
}

// ---------------- output head: out[m] = x[m,:] . W_out + b_out (fp32 out) ---
__global__ __launch_bounds__(256) void out_proj(const u16* __restrict__ x,
                                                const float* __restrict__ wout,
                                                const float* __restrict__ bout,
                                                float* __restrict__ out) {
  int wave = threadIdx.x >> 6, lane = threadIdx.x & 63;
  int m = blockIdx.x * 4 + wave;
  union { uint4 vv; u16 s[8]; } xv;
  xv.vv = *(const uint4*)&x[(size_t)m * EMB + lane * 8];
  float4 w0 = *(const float4*)&wout[lane * 8];
  float4 w1 = *(const float4*)&wout[lane * 8 + 4];
  float wv[8] = {w0.x, w0.y, w0.z, w0.w, w1.x, w1.y, w1.z, w1.w};
  float s = 0.f;
#pragma unroll
  for (int j = 0; j < 8; ++j) s += bf2f(xv.s[j]) * wv[j];
#pragma unroll
  for (int sh = 1; sh < 64; sh <<= 1) s += __shfl_xor(s, sh, 64);
  if (lane == 0) out[m] = s + bout[0];
}

extern "C" void kernel_launch(void* const* d_in, const int* in_sizes, int n_in,
                              void* d_out, int out_size, void* d_ws, size_t ws_size,
                              hipStream_t stream) {
  const int*   inp   = (const int*)d_in[0];
  const float* table = (const float*)d_in[1];
  const float* Wq    = (const float*)d_in[2];
  const float* bq    = (const float*)d_in[3];
  const float* Wk    = (const float*)d_in[4];
  const float* bk    = (const float*)d_in[5];
  const float* Wv    = (const float*)d_in[6];
  const float* bv    = (const float*)d_in[7];
  const float* Wo    = (const float*)d_in[8];
  const float* bo    = (const float*)d_in[9];
  const float* Wout  = (const float*)d_in[10];
  const float* bout  = (const float*)d_in[11];
  float* outp = (float*)d_out;

  char* ws = (char*)d_ws;
  const size_t SZ = (size_t)M_ROWS * EMB * 2;  // 32 MB
  u16* x      = (u16*)(ws);
  u16* qb     = (u16*)(ws + SZ);
  u16* kb     = (u16*)(ws + 2 * SZ);
  u16* vb     = (u16*)(ws + 3 * SZ);   // [B,H,D,S]
  u16* attn_b = (u16*)(ws + 4 * SZ);
  u16* WtQKV  = (u16*)(ws + 5 * SZ);
  u16* WtO    = (u16*)(ws + 5 * SZ + (size_t)NLAYER * 3 * EMB * EMB * 2);

  prep_weights<<<8192, 256, 0, stream>>>(Wq, Wk, Wv, Wo, WtQKV, WtO);
  embed_pe<<<M_ROWS, 256, 0, stream>>>(inp, table, x);

  for (int l = 0; l < NLAYER; ++l) {
    gemm_bt<<<3072, 256, 0, stream>>>(
        x, WtQKV + (size_t)l * 3 * EMB * EMB, EMB, /*mode=*/0,
        bq + l * EMB, bk + l * EMB, bv + l * EMB, qb, kb, vb, nullptr, 0);
    attn_kernel<<<4096, 256, 0, stream>>>(qb, kb, vb, attn_b);
    gemm_bt<<<1024, 256, 0, stream>>>(
        attn_b, WtO + (size_t)l * EMB * EMB, EMB, /*mode=*/1,
        bo + l * EMB, nullptr, nullptr, x, nullptr, nullptr, x, EMB);
  }
  out_proj<<<8192, 256, 0, stream>>>(x, Wout, bout, outp);
}

// Round 12
// 641.942 us; speedup vs baseline: 1.5560x; 1.0334x over previous
//
#include <hip/hip_runtime.h>

typedef unsigned short u16;
typedef unsigned int u32;
using short8  = __attribute__((ext_vector_type(8))) short;
using floatx4 = __attribute__((ext_vector_type(4))) float;

#define NB 32
#define SEQ 1024
#define EMB 512
#define NH 8
#define HD 64
#define NLAYER 2
#define M_ROWS (NB * SEQ)   // 32768

__device__ __forceinline__ float bf2f(u16 u) {
  union { u32 i; float f; } v; v.i = ((u32)u) << 16; return v.f;
}
__device__ __forceinline__ u16 f2bf(float f) {
  union { float f; u32 i; } v; v.f = f;
  u32 r = v.i + 0x7fffu + ((v.i >> 16) & 1u);
  return (u16)(r >> 16);
}

// async global->LDS, 16B per lane. LDS dest = wave-uniform base + lane*16.
typedef __attribute__((address_space(3))) unsigned int lds_u32_t;
typedef __attribute__((address_space(1))) const unsigned int gbl_u32_t;
__device__ __forceinline__ void gload16(void* lds, const void* g) {
  gbl_u32_t* gp = (gbl_u32_t*)(unsigned long long)g;
  lds_u32_t* lp = (lds_u32_t*)(unsigned int)(unsigned long long)lds;
  __builtin_amdgcn_global_load_lds(gp, lp, 16, 0, 0);
}

// ---------------- weight pre-transpose + fp32->bf16: W[K,N] -> Bt[N,K] ------
__global__ void prep_weights(const float* __restrict__ Wq, const float* __restrict__ Wk,
                             const float* __restrict__ Wv, const float* __restrict__ Wo,
                             u16* __restrict__ WtQKV, u16* __restrict__ WtO) {
  int idx = blockIdx.x * 256 + threadIdx.x;
  const int QKV_TOT = NLAYER * 3 * EMB * EMB;
  if (idx < QKV_TOT) {
    int l = idx / (3 * EMB * EMB);
    int rem = idx % (3 * EMB * EMB);
    int n = rem / EMB, kk = rem % EMB;
    int w = n >> 9, e = n & 511;
    const float* src = (w == 0) ? Wq : (w == 1) ? Wk : Wv;
    WtQKV[idx] = f2bf(src[((size_t)l * EMB + kk) * EMB + e]);
  } else {
    int j = idx - QKV_TOT;
    int l = j / (EMB * EMB);
    int rem = j % (EMB * EMB);
    int n = rem / EMB, kk = rem % EMB;
    WtO[j] = f2bf(Wo[((size_t)l * EMB + kk) * EMB + n]);
  }
}

// ---------------- embedding + positional encoding (fp32 in, bf16 out) -------
__global__ void embed_pe(const int* __restrict__ inp, const float* __restrict__ table,
                         u16* __restrict__ x) {
  int row = blockIdx.x;
  int tok = inp[row];
  int s = row & (SEQ - 1);
  const float negln = -9.210340371976184f / (float)EMB;
  for (int e = threadIdx.x; e < EMB; e += blockDim.x) {
    float val = table[(size_t)tok * EMB + e];
    int i = e >> 1;
    float dt = __expf((float)(2 * i) * negln);
    float ang = (float)s * dt;
    float pe = (e & 1) ? __cosf(ang) : __sinf(ang);
    x[(size_t)row * EMB + e] = f2bf(val + pe);
  }
}

// ---------------- GEMM: C[M,N] = A[M,K] @ Bt[N,K]^T + bias ------------------
// XCD-aware 1-D grid. Double-buffered K-loop (vmcnt(4) + raw s_barrier),
// lgkmcnt(0) before the trailing barrier closes the read-in-flight race.
// Epilogue: per-wave LDS repack -> coalesced 128B dword-row stores.
// mode 0: N=1536 (NT=12). Q (*0.125 folded), K -> [B,H,S,D]; V (bn0>=1024):
//         operand-swapped MFMA -> [B,H,D,S] stores sid-contiguous.
// mode 1: N=512 (NT=4),  x = x + relu(C + bias)  (in place, out0 == resid)
#define BK 32

__global__ __launch_bounds__(256) void gemm_bt(
    const u16* __restrict__ A, const u16* __restrict__ Bt, int K, int mode,
    const float* bias0, const float* bias1, const float* bias2,
    u16* out0, u16* out1, u16* out2, const u16* resid, int Nstride) {
  __shared__ u16 sA[2][128][BK];
  __shared__ u16 sB[2][128][BK];
  int tid = threadIdx.x;
  int wave = tid >> 6, lane = tid & 63;
  int quad = lane >> 4, l16 = lane & 15;
  int wm = wave >> 1, wn = wave & 1;

  int NT = (mode == 0) ? 12 : 4;          // N-tiles per M-tile
  int blk = blockIdx.x;
  int xcd = blk & 7, slot = blk >> 3;
  int mtl = slot / NT, ntl = slot % NT;   // 32 M-tiles per XCD, N-tiles inner
  int bm0 = (xcd * 32 + mtl) * 128;
  int bn0 = ntl * 128;
  bool vswap = (mode == 0) && (bn0 >= 1024);

  floatx4 acc[4][4];
#pragma unroll
  for (int i = 0; i < 4; ++i)
#pragma unroll
    for (int j = 0; j < 4; ++j) acc[i][j] = (floatx4){0.f, 0.f, 0.f, 0.f};

  int rb = wave * 32;                         // wave stages rows rb..rb+31
  int lrow = lane >> 2;                       // 0..15
  int gcg = ((lane & 3) ^ ((lane >> 3) & 3)) * 8;  // fetch chunk for slot lane&3
  int rsl = (quad ^ ((l16 >> 1) & 3)) * 8;    // read slot holding chunk `quad`

  const u16* Arow0 = &A[(size_t)(bm0 + rb + lrow) * K + gcg];
  const u16* Arow1 = &A[(size_t)(bm0 + rb + 16 + lrow) * K + gcg];
  const u16* Brow0 = &Bt[(size_t)(bn0 + rb + lrow) * K + gcg];
  const u16* Brow1 = &Bt[(size_t)(bn0 + rb + 16 + lrow) * K + gcg];

  // prologue: stage k-tile 0 into buffer 0 (4 loads per wave)
  gload16(&sA[0][rb][0],      Arow0);
  gload16(&sA[0][rb + 16][0], Arow1);
  gload16(&sB[0][rb][0],      Brow0);
  gload16(&sB[0][rb + 16][0], Brow1);

  const int niter = K / BK;
  int ibuf = 0;
  for (int it = 0; it < niter; ++it) {
    if (it + 1 < niter) {
      int k1 = (it + 1) * BK;
      int nb = ibuf ^ 1;
      gload16(&sA[nb][rb][0],      Arow0 + k1);
      gload16(&sA[nb][rb + 16][0], Arow1 + k1);
      gload16(&sB[nb][rb][0],      Brow0 + k1);
      gload16(&sB[nb][rb + 16][0], Brow1 + k1);
      asm volatile("s_waitcnt vmcnt(4)" ::: "memory");  // current buf's 4 done
    } else {
      asm volatile("s_waitcnt vmcnt(0)" ::: "memory");
    }
    asm volatile("s_barrier" ::: "memory");             // buf ready for all

    short8 af[4], bfr[4];
#pragma unroll
    for (int mi = 0; mi < 4; ++mi)
      af[mi] = *(const short8*)&sA[ibuf][wm * 64 + mi * 16 + l16][rsl];
#pragma unroll
    for (int ni = 0; ni < 4; ++ni)
      bfr[ni] = *(const short8*)&sB[ibuf][wn * 64 + ni * 16 + l16][rsl];
    if (!vswap) {
#pragma unroll
      for (int mi = 0; mi < 4; ++mi)
#pragma unroll
        for (int ni = 0; ni < 4; ++ni)
          acc[mi][ni] = __builtin_amdgcn_mfma_f32_16x16x32_bf16(af[mi], bfr[ni], acc[mi][ni], 0, 0, 0);
    } else {
#pragma unroll
      for (int mi = 0; mi < 4; ++mi)
#pragma unroll
        for (int ni = 0; ni < 4; ++ni)
          acc[mi][ni] = __builtin_amdgcn_mfma_f32_16x16x32_bf16(bfr[ni], af[mi], acc[mi][ni], 0, 0, 0);
    }
    asm volatile("s_waitcnt lgkmcnt(0)" ::: "memory");  // all ds_reads complete
    asm volatile("s_barrier" ::: "memory");             // before buf overwrite
    ibuf ^= 1;
  }

  // ---- epilogue: wave-private LDS repack -> coalesced dword-row stores ----
  u16* scr = ((u16*)sA) + wave * (16 * 68);
  int erow = lane >> 5;            // 0..1: row within a read pass
  int dcol = lane & 31;            // dword column (2 bf16 per dword)

  if (!vswap) {
    int w = bn0 >> 9;                                   // 0=Q, 1=K (mode 0)
    const float* bp = (mode == 1) ? bias0 : ((w == 0) ? bias0 : bias1);
    float sc = (mode == 0 && w == 0) ? 0.125f : 1.0f;   // fold 1/sqrt(D) into Q
    float bv[4];
#pragma unroll
    for (int ni = 0; ni < 4; ++ni)
      bv[ni] = bp[(bn0 + wn * 64 + ni * 16 + l16) & 511];

#pragma unroll
    for (int mi = 0; mi < 4; ++mi) {
#pragma unroll
      for (int ni = 0; ni < 4; ++ni)
#pragma unroll
        for (int r = 0; r < 4; ++r) {
          float t = (acc[mi][ni][r] + bv[ni]) * sc;
          if (mode == 1) t = fmaxf(t, 0.f);
          scr[(quad * 4 + r) * 68 + ni * 16 + l16] = f2bf(t);
        }
      asm volatile("s_waitcnt lgkmcnt(0)" ::: "memory");  // wave-private: no barrier

      int m0 = bm0 + wm * 64 + mi * 16;
      int colg = bn0 + wn * 64 + dcol * 2;
#pragma unroll
      for (int p = 0; p < 8; ++p) {
        int row = p * 2 + erow;
        u32 d2 = *(const u32*)&scr[row * 68 + dcol * 2];
        int m = m0 + row;
        if (mode == 0) {
          int e = colg & 511, h = e >> 6, d = e & 63;
          int b = m >> 10, sid = m & 1023;
          u16* optr = (w == 0) ? out0 : out1;
          *(u32*)&optr[((size_t)(b * NH + h) * SEQ + sid) * HD + d] = d2;
        } else {
          size_t off = (size_t)m * Nstride + colg;
          u32 rs = *(const u32*)&resid[off];
          float lo = bf2f((u16)d2) + bf2f((u16)rs);
          float hi = bf2f((u16)(d2 >> 16)) + bf2f((u16)(rs >> 16));
          *(u32*)&out0[off] = ((u32)f2bf(hi) << 16) | f2bf(lo);
        }
      }
      asm volatile("s_waitcnt lgkmcnt(0)" ::: "memory");  // reads done before rewrite
    }
  } else {
    // V section: D rows = weight rows (d), D cols = x rows (sid)
    float bvv[4][4];
#pragma unroll
    for (int ni = 0; ni < 4; ++ni)
#pragma unroll
      for (int r = 0; r < 4; ++r)
        bvv[ni][r] = bias2[(bn0 + wn * 64 + ni * 16 + quad * 4 + r) & 511];

    int b = (bm0 + wm * 64) >> 10;
    int sid0 = (bm0 + wm * 64) & 1023;
    int n0 = bn0 + wn * 64;
    int h = (n0 >> 6) & 7;
#pragma unroll
    for (int ni = 0; ni < 4; ++ni) {
#pragma unroll
      for (int mi = 0; mi < 4; ++mi)
#pragma unroll
        for (int r = 0; r < 4; ++r)
          scr[(quad * 4 + r) * 68 + mi * 16 + l16] = f2bf(acc[mi][ni][r] + bvv[ni][r]);
      asm volatile("s_waitcnt lgkmcnt(0)" ::: "memory");

      int d0 = (n0 & 63) + ni * 16;
#pragma unroll
      for (int p = 0; p < 8; ++p) {
        int row = p * 2 + erow;
        u32 d2 = *(const u32*)&scr[row * 68 + dcol * 2];
        *(u32*)&out2[((size_t)(b * NH + h) * HD + d0 + row) * SEQ + sid0 + dcol * 2] = d2;
      }
      asm volatile("s_waitcnt lgkmcnt(0)" ::: "memory");
    }
  }
}

// ---------------- flash attention, causal ----------------------------------
// 2 Q-tiles per block (128 q rows): K/V staging + barriers serve 2x work.
// No running max: scores are O(+-8) analytically; p = exp(min(s,75)), masked
// lanes = 0. Row sums via ones-MFMA. Q pre-scaled by 1/8 in QKV epilogue.
__device__ __forceinline__ void stage_tile64(u16 (*dst)[64], const u16* g, int gstride,
                                             int wave, int lane) {
  int r = lane >> 3;
  int gcg = ((lane & 7) ^ r) * 8;
#pragma unroll
  for (int c = 0; c < 2; ++c) {
    int row0 = (wave * 2 + c) * 8;
    gload16(&dst[row0][0], &g[(size_t)(row0 + r) * gstride + gcg]);
  }
}
#define RD8(T, row, cg) (*(const short8*)&T[row][(((cg) ^ ((row) & 7)) * 8)])

__global__ __launch_bounds__(256) void attn_kernel(
    const u16* __restrict__ q, const u16* __restrict__ k, const u16* __restrict__ vt,
    u16* __restrict__ o) {
  int blk = blockIdx.x;          // 0..2047
  int xcd = blk & 7, slot = blk >> 3;
  int bh = xcd * 32 + (slot >> 3);   // 8 qtile-pair blocks per bh, consecutive
  int qtp = slot & 7;
  int b = bh >> 3, h = bh & 7;
  int qA0 = qtp * 128, qB0 = qA0 + 64;
  __shared__ u16 sQ[128][64], sK[64][64], sV[64][64];
  __shared__ u16 sP[2][64][68];
  int tid = threadIdx.x, wave = tid >> 6, lane = tid & 63;
  int quad = lane >> 4, l16 = lane & 15;

  stage_tile64((u16(*)[64])&sQ[0][0],  &q[((size_t)bh * SEQ + qA0) * HD], HD, wave, lane);
  stage_tile64((u16(*)[64])&sQ[64][0], &q[((size_t)bh * SEQ + qB0) * HD], HD, wave, lane);

  short8 ones;
#pragma unroll
  for (int j = 0; j < 8; ++j) ones[j] = (short)0x3F80;   // bf16 1.0

  floatx4 accoA[4], accoB[4], accsumA, accsumB;
#pragma unroll
  for (int i = 0; i < 4; ++i) {
    accoA[i] = (floatx4){0.f, 0.f, 0.f, 0.f};
    accoB[i] = (floatx4){0.f, 0.f, 0.f, 0.f};
  }
  accsumA = (floatx4){0.f, 0.f, 0.f, 0.f};
  accsumB = (floatx4){0.f, 0.f, 0.f, 0.f};
  short8 aqA0 = {}, aqA1 = {}, aqB0 = {}, aqB1 = {};

  // one sub-tile pass: S = Q@K^T (pre-scaled), p = exp(s) (masked->0),
  // P->LDS->A-layout, PV + ones-MFMA row sums.
  auto process = [&](short8 aq0, short8 aq1, int qX0, bool diag, int sub,
                     floatx4* acco, floatx4& accsum, int k0) {
    floatx4 accs[4];
#pragma unroll
    for (int i = 0; i < 4; ++i) accs[i] = (floatx4){0.f, 0.f, 0.f, 0.f};
#pragma unroll
    for (int nt = 0; nt < 4; ++nt) {
      int rbk = nt * 16 + l16;
      accs[nt] = __builtin_amdgcn_mfma_f32_16x16x32_bf16(aq0, RD8(sK, rbk, quad), accs[nt], 0, 0, 0);
      accs[nt] = __builtin_amdgcn_mfma_f32_16x16x32_bf16(aq1, RD8(sK, rbk, 4 + quad), accs[nt], 0, 0, 0);
    }
    int qg_base = qX0 + wave * 16 + quad * 4;
#pragma unroll
    for (int nt = 0; nt < 4; ++nt) {
      int kg = k0 + nt * 16 + l16;
#pragma unroll
      for (int r = 0; r < 4; ++r) {
        float p = __expf(fminf(accs[nt][r], 75.f));
        if (diag && kg > qg_base + r) p = 0.f;
        sP[sub][wave * 16 + quad * 4 + r][nt * 16 + l16] =
            (u16)(__float_as_uint(p) >> 16);   // truncate bf16
      }
    }
    asm volatile("s_waitcnt lgkmcnt(0)" ::: "memory");   // wave-private rows
#pragma unroll
    for (int cst = 0; cst < 2; ++cst) {
      short8 ap = *(const short8*)&sP[sub][wave * 16 + l16][cst * 32 + quad * 8];
#pragma unroll
      for (int dt = 0; dt < 4; ++dt) {
        int rv = dt * 16 + l16;
        acco[dt] = __builtin_amdgcn_mfma_f32_16x16x32_bf16(ap, RD8(sV, rv, cst * 4 + quad), acco[dt], 0, 0, 0);
      }
      accsum = __builtin_amdgcn_mfma_f32_16x16x32_bf16(ap, ones, accsum, 0, 0, 0);
    }
  };

  int ktmax = 2 * qtp + 1;
  for (int kt = 0; kt <= ktmax; ++kt) {
    int k0 = kt * 64;
    __syncthreads();   // previous iter's sK/sV reads done (and sQ at kt=0)
    stage_tile64(sK, &k[((size_t)bh * SEQ + k0) * HD], HD, wave, lane);
    stage_tile64(sV, &vt[(size_t)bh * HD * SEQ + k0], SEQ, wave, lane);
    __syncthreads();   // drains vmcnt -> staged data visible

    if (kt == 0) {     // hoist Q fragments (wave-private rows of sQ)
      int ra = wave * 16 + l16;
      aqA0 = RD8(sQ, ra, quad);
      aqA1 = RD8(sQ, ra, 4 + quad);
      int rb_ = 64 + wave * 16 + l16;
      aqB0 = RD8(sQ, rb_, quad);
      aqB1 = RD8(sQ, rb_, 4 + quad);
    }

    if (kt <= 2 * qtp)
      process(aqA0, aqA1, qA0, kt == 2 * qtp, 0, accoA, accsumA, k0);
    process(aqB0, aqB1, qB0, kt == ktmax, 1, accoB, accsumB, k0);
  }

  // normalize + write [B,S,E], both sub-tiles
#pragma unroll
  for (int dt = 0; dt < 4; ++dt)
#pragma unroll
    for (int r = 0; r < 4; ++r) {
      int rowoff = wave * 16 + quad * 4 + r;
      int col = h * HD + dt * 16 + l16;
      o[((size_t)b * SEQ + qA0 + rowoff) * EMB + col] = f2bf(accoA[dt][r] / accsumA[r]);
      o[((size_t)b * SEQ + qB0 + rowoff) * EMB + col] = f2bf(accoB[dt][r] / accsumB[r]);
    }
}

// ---------------- output head: out[m] = x[m,:] . W_out + b_out (fp32 out) ---
__global__ __launch_bounds__(256) void out_proj(const u16* __restrict__ x,
                                                const float* __restrict__ wout,
                                                const float* __restrict__ bout,
                                                float* __restrict__ out) {
  int wave = threadIdx.x >> 6, lane = threadIdx.x & 63;
  int m = blockIdx.x * 4 + wave;
  union { uint4 vv; u16 s[8]; } xv;
  xv.vv = *(const uint4*)&x[(size_t)m * EMB + lane * 8];
  float4 w0 = *(const float4*)&wout[lane * 8];
  float4 w1 = *(const float4*)&wout[lane * 8 + 4];
  float wv[8] = {w0.x, w0.y, w0.z, w0.w, w1.x, w1.y, w1.z, w1.w};
  float s = 0.f;
#pragma unroll
  for (int j = 0; j < 8; ++j) s += bf2f(xv.s[j]) * wv[j];
#pragma unroll
  for (int sh = 1; sh < 64; sh <<= 1) s += __shfl_xor(s, sh, 64);
  if (lane == 0) out[m] = s + bout[0];
}

extern "C" void kernel_launch(void* const* d_in, const int* in_sizes, int n_in,
                              void* d_out, int out_size, void* d_ws, size_t ws_size,
                              hipStream_t stream) {
  const int*   inp   = (const int*)d_in[0];
  const float* table = (const float*)d_in[1];
  const float* Wq    = (const float*)d_in[2];
  const float* bq    = (const float*)d_in[3];
  const float* Wk    = (const float*)d_in[4];
  const float* bk    = (const float*)d_in[5];
  const float* Wv    = (const float*)d_in[6];
  const float* bv    = (const float*)d_in[7];
  const float* Wo    = (const float*)d_in[8];
  const float* bo    = (const float*)d_in[9];
  const float* Wout  = (const float*)d_in[10];
  const float* bout  = (const float*)d_in[11];
  float* outp = (float*)d_out;

  char* ws = (char*)d_ws;
  const size_t SZ = (size_t)M_ROWS * EMB * 2;  // 32 MB
  u16* x      = (u16*)(ws);
  u16* qb     = (u16*)(ws + SZ);
  u16* kb     = (u16*)(ws + 2 * SZ);
  u16* vb     = (u16*)(ws + 3 * SZ);   // [B,H,D,S]
  u16* attn_b = (u16*)(ws + 4 * SZ);
  u16* WtQKV  = (u16*)(ws + 5 * SZ);
  u16* WtO    = (u16*)(ws + 5 * SZ + (size_t)NLAYER * 3 * EMB * EMB * 2);

  prep_weights<<<8192, 256, 0, stream>>>(Wq, Wk, Wv, Wo, WtQKV, WtO);
  embed_pe<<<M_ROWS, 256, 0, stream>>>(inp, table, x);

  for (int l = 0; l < NLAYER; ++l) {
    gemm_bt<<<3072, 256, 0, stream>>>(
        x, WtQKV + (size_t)l * 3 * EMB * EMB, EMB, /*mode=*/0,
        bq + l * EMB, bk + l * EMB, bv + l * EMB, qb, kb, vb, nullptr, 0);
    attn_kernel<<<2048, 256, 0, stream>>>(qb, kb, vb, attn_b);
    gemm_bt<<<1024, 256, 0, stream>>>(
        attn_b, WtO + (size_t)l * EMB * EMB, EMB, /*mode=*/1,
        bo + l * EMB, nullptr, nullptr, x, nullptr, nullptr, x, EMB);
  }
  out_proj<<<8192, 256, 0, stream>>>(x, Wout, bout, outp);
}